// Round 22
// baseline (9623.109 us; speedup 1.0000x reference)
//
#include <hip/hip_runtime.h>
#include <hip/hip_bf16.h>
#include <math.h>

using bf16 = __hip_bfloat16;
typedef __attribute__((ext_vector_type(8))) short short8;
typedef __attribute__((ext_vector_type(4))) float f32x4;
typedef __attribute__((ext_vector_type(4))) unsigned short u16x4;

#define DEVFN __device__ __forceinline__

DEVFN float bf2f(bf16 v) { return __bfloat162float(v); }
DEVFN bf16  f2bf(float v) { return __float2bfloat16(v); }

// ---------------------------------------------------------------- f32 -> bf16
__global__ __launch_bounds__(256) void cvt_kernel(const float* __restrict__ in, bf16* __restrict__ out, int n)
{
  int i = blockIdx.x * 256 + threadIdx.x;
  if (i < n) out[i] = f2bf(in[i]);
}

// fused QKV weight+bias conversion
__global__ __launch_bounds__(256) void cvt_qkv(const float* __restrict__ wq,
    const float* __restrict__ wk, const float* __restrict__ wv,
    const float* __restrict__ bq, const float* __restrict__ bk, const float* __restrict__ bv,
    bf16* __restrict__ out, float* __restrict__ bout)
{
  int i = blockIdx.x * 256 + threadIdx.x;       // 1,769,472 weights + 2304 bias
  if (i < 589824)            out[i] = f2bf(wq[i]);
  else if (i < 1179648)      out[i] = f2bf(wk[i - 589824]);
  else if (i < 1769472)      out[i] = f2bf(wv[i - 1179648]);
  else if (i < 1771776) {
    int j = i - 1769472;
    bout[j] = (j < 768) ? bq[j] : (j < 1536) ? bk[j - 768] : bv[j - 1536];
  }
}

// enc_w column permutation: out[n][pos*64+co] = in[n][co*49+pos]  (768 x 3136)
__global__ __launch_bounds__(256) void cvt_enc(const float* __restrict__ in, bf16* __restrict__ out)
{
  int i = blockIdx.x * 256 + threadIdx.x;       // 2,408,448 = 9408*256 exact
  int n = i / 3136, kp = i - n * 3136;
  int pos = kp >> 6, co = kp & 63;
  out[i] = f2bf(in[n * 3136 + co * 49 + pos]);
}

// ---------------------------------------------------------------- im2col kernels (per 512-image chunk)
__global__ __launch_bounds__(256) void im2col1(const float* __restrict__ states, bf16* __restrict__ P1)
{
  int idx = blockIdx.x * 256 + threadIdx.x;     // 13,107,200 = 51,200*256 exact
  int row = idx >> 6, k = idx & 63;
  int imgL = row / 400, pos = row - imgL * 400;
  int oy = pos / 20, ox = pos - oy * 20;
  int ky = k >> 3, kx = k & 7;
  float v = states[(size_t)imgL * 7056 + (oy * 4 + ky) * 84 + ox * 4 + kx] * (1.0f / 255.0f);
  P1[idx] = f2bf(v);
}

__global__ __launch_bounds__(256) void im2col2(const bf16* __restrict__ C1, bf16* __restrict__ P2)
{
  int idx = blockIdx.x * 256 + threadIdx.x;     // 21,233,664 = 82,944*256 exact
  int row = idx >> 9, k = idx & 511;
  int imgL = row / 81, pos = row - imgL * 81;
  int oy = pos / 9, ox = pos - oy * 9;
  int ci = k >> 4, r = k & 15, ky = r >> 2, kx = r & 3;
  P2[idx] = C1[((size_t)imgL * 400 + (oy * 2 + ky) * 20 + ox * 2 + kx) * 32 + ci];
}

__global__ __launch_bounds__(256) void im2col3(const bf16* __restrict__ C2, bf16* __restrict__ P3)
{
  int idx = blockIdx.x * 256 + threadIdx.x;     // 14,450,688 = 56,448*256 exact
  int row = idx / 576, k = idx - row * 576;
  int imgL = row / 49, pos = row - imgL * 49;
  int oy = pos / 7, ox = pos - oy * 7;
  int ci = k / 9, r = k - ci * 9;
  int ky = r / 3, kx = r - ky * 3;
  P3[idx] = C2[((size_t)imgL * 81 + (oy + ky) * 9 + ox + kx) * 64 + ci];
}

// ---------------------------------------------------------------- MFMA GEMM, 128x64 tile
// out = act(A @ W^T + bias). ACT: 0 none, 1 tanh, 2 gelu, 3 relu. OUTMODE: 0 bf16, 1 f32, 2 f32 +=
template<int ACT, int OUTMODE>
__global__ __launch_bounds__(256) void gemm_bt64(
    const bf16* __restrict__ A, const bf16* __restrict__ W,
    const float* __restrict__ bias, void* __restrict__ outp,
    int M, int N, int K)
{
  __shared__ bf16 As[128*64];
  __shared__ bf16 Bs[64*64];
  const int tid = threadIdx.x;
  const int lane = tid & 63, wave = tid >> 6;
  const int m0 = blockIdx.x * 128, n0 = blockIdx.y * 64;
  const int wm = wave * 32;
  const int l16 = lane & 15, l4 = lane >> 4;
  f32x4 acc[2][4];
  #pragma unroll
  for (int i = 0; i < 2; ++i)
    #pragma unroll
    for (int j = 0; j < 4; ++j) { f32x4 z = {0.f,0.f,0.f,0.f}; acc[i][j] = z; }

  for (int k0 = 0; k0 < K; k0 += 64) {
    __syncthreads();
    #pragma unroll
    for (int it = 0; it < 4; ++it) {          // A: 128x64 = 1024 slots of 8
      int f = it*256 + tid;
      int row = f >> 3, col = (f & 7) << 3;
      const bf16* ga = A + (size_t)(m0 + row) * K + k0 + col;
      __builtin_amdgcn_global_load_lds((const __attribute__((address_space(1))) void*)ga,
                                       (__attribute__((address_space(3))) void*)(As + f*8), 16, 0, 0);
    }
    #pragma unroll
    for (int it = 0; it < 2; ++it) {          // B: 64x64 = 512 slots of 8
      int f = it*256 + tid;
      int row = f >> 3, col = (f & 7) << 3;
      const bf16* gb = W + (size_t)(n0 + row) * K + k0 + col;
      __builtin_amdgcn_global_load_lds((const __attribute__((address_space(1))) void*)gb,
                                       (__attribute__((address_space(3))) void*)(Bs + f*8), 16, 0, 0);
    }
    __syncthreads();
    #pragma unroll
    for (int kk = 0; kk < 2; ++kk) {
      short8 af[2], bfr[4];
      #pragma unroll
      for (int i = 0; i < 2; ++i) af[i]  = *(const short8*)(As + (wm + i*16 + l16)*64 + kk*32 + l4*8);
      #pragma unroll
      for (int j = 0; j < 4; ++j) bfr[j] = *(const short8*)(Bs + (j*16 + l16)*64 + kk*32 + l4*8);
      #pragma unroll
      for (int i = 0; i < 2; ++i)
        #pragma unroll
        for (int j = 0; j < 4; ++j)
          acc[i][j] = __builtin_amdgcn_mfma_f32_16x16x32_bf16(af[i], bfr[j], acc[i][j], 0, 0, 0);
    }
  }
  #pragma unroll
  for (int i = 0; i < 2; ++i)
    #pragma unroll
    for (int j = 0; j < 4; ++j)
      #pragma unroll
      for (int r = 0; r < 4; ++r) {
        int grow = m0 + wm + i*16 + l4*4 + r;
        int gcol = n0 + j*16 + l16;
        if (grow < M && gcol < N) {
          float v = acc[i][j][r] + bias[gcol];
          if (ACT == 1) v = tanhf(v);
          else if (ACT == 2) v = 0.5f * v * (1.0f + erff(v * 0.70710678118654752f));
          else if (ACT == 3) v = fmaxf(v, 0.0f);
          size_t idx = (size_t)grow * N + gcol;
          if (OUTMODE == 0)      ((bf16*)outp)[idx] = f2bf(v);
          else if (OUTMODE == 1) ((float*)outp)[idx] = v;
          else                   ((float*)outp)[idx] += v;
        }
      }
}

// ---------------------------------------------------------------- MFMA GEMM, 128x192 tile
// 3 B-chunks (64 cols each) share one A-stage per K-step: 3x arithmetic intensity on A.
// Same fragment math / K-order as gemm_bt64 -> bit-identical results. LDS 40KB -> 3 blocks/CU.
template<int ACT, int OUTMODE>
__global__ __launch_bounds__(256) void gemm_bt192(
    const bf16* __restrict__ A, const bf16* __restrict__ W,
    const float* __restrict__ bias, void* __restrict__ outp,
    int M, int N, int K)
{
  __shared__ bf16 As[128*64];
  __shared__ bf16 Bs[3*64*64];
  const int tid = threadIdx.x;
  const int lane = tid & 63, wave = tid >> 6;
  const int m0 = blockIdx.x * 128, n0 = blockIdx.y * 192;
  const int wm = wave * 32;
  const int l16 = lane & 15, l4 = lane >> 4;
  f32x4 acc[2][12];
  #pragma unroll
  for (int i = 0; i < 2; ++i)
    #pragma unroll
    for (int j = 0; j < 12; ++j) { f32x4 z = {0.f,0.f,0.f,0.f}; acc[i][j] = z; }

  for (int k0 = 0; k0 < K; k0 += 64) {
    __syncthreads();
    #pragma unroll
    for (int it = 0; it < 4; ++it) {          // A: 128x64 = 1024 slots of 8
      int f = it*256 + tid;
      int row = f >> 3, col = (f & 7) << 3;
      const bf16* ga = A + (size_t)(m0 + row) * K + k0 + col;
      __builtin_amdgcn_global_load_lds((const __attribute__((address_space(1))) void*)ga,
                                       (__attribute__((address_space(3))) void*)(As + f*8), 16, 0, 0);
    }
    #pragma unroll
    for (int it = 0; it < 6; ++it) {          // B: 3 chunks x 64x64 = 1536 slots of 8
      int f = it*256 + tid;
      int row = f >> 3, col = (f & 7) << 3;   // row in [0,192)
      const bf16* gb = W + (size_t)(n0 + row) * K + k0 + col;
      __builtin_amdgcn_global_load_lds((const __attribute__((address_space(1))) void*)gb,
                                       (__attribute__((address_space(3))) void*)(Bs + f*8), 16, 0, 0);
    }
    __syncthreads();
    #pragma unroll
    for (int kk = 0; kk < 2; ++kk) {
      short8 af[2];
      #pragma unroll
      for (int i = 0; i < 2; ++i) af[i] = *(const short8*)(As + (wm + i*16 + l16)*64 + kk*32 + l4*8);
      #pragma unroll
      for (int c = 0; c < 3; ++c) {
        short8 bfr[4];
        #pragma unroll
        for (int j = 0; j < 4; ++j)
          bfr[j] = *(const short8*)(Bs + c*4096 + (j*16 + l16)*64 + kk*32 + l4*8);
        #pragma unroll
        for (int i = 0; i < 2; ++i)
          #pragma unroll
          for (int j = 0; j < 4; ++j)
            acc[i][c*4 + j] = __builtin_amdgcn_mfma_f32_16x16x32_bf16(af[i], bfr[j], acc[i][c*4 + j], 0, 0, 0);
      }
    }
  }
  #pragma unroll
  for (int i = 0; i < 2; ++i)
    #pragma unroll
    for (int c = 0; c < 3; ++c)
      #pragma unroll
      for (int j = 0; j < 4; ++j)
        #pragma unroll
        for (int r = 0; r < 4; ++r) {
          int grow = m0 + wm + i*16 + l4*4 + r;
          int gcol = n0 + c*64 + j*16 + l16;
          if (grow < M && gcol < N) {
            float v = acc[i][c*4 + j][r] + bias[gcol];
            if (ACT == 1) v = tanhf(v);
            else if (ACT == 2) v = 0.5f * v * (1.0f + erff(v * 0.70710678118654752f));
            else if (ACT == 3) v = fmaxf(v, 0.0f);
            size_t idx = (size_t)grow * N + gcol;
            if (OUTMODE == 0)      ((bf16*)outp)[idx] = f2bf(v);
            else if (OUTMODE == 1) ((float*)outp)[idx] = v;
            else                   ((float*)outp)[idx] += v;
          }
        }
}

// ---------------------------------------------------------------- LayerNorm -> bf16
__global__ __launch_bounds__(256) void ln_kernel(const float* __restrict__ x,
    const float* __restrict__ g, const float* __restrict__ b,
    bf16* __restrict__ out, int rows)
{
  int wave = threadIdx.x >> 6, lane = threadIdx.x & 63;
  int row = blockIdx.x * 4 + wave;
  if (row >= rows) return;
  const float* xr = x + (size_t)row * 768;
  float v[12]; float s = 0.f, s2 = 0.f;
  #pragma unroll
  for (int j = 0; j < 12; ++j) { float t = xr[j*64 + lane]; v[j] = t; s += t; s2 = fmaf(t, t, s2); }
  #pragma unroll
  for (int off = 32; off; off >>= 1) { s += __shfl_xor(s, off); s2 += __shfl_xor(s2, off); }
  float mean = s * (1.0f/768.0f);
  float var  = s2 * (1.0f/768.0f) - mean*mean;
  float rs   = rsqrtf(var + 1e-5f);
  bf16* orow = out + (size_t)row * 768;
  #pragma unroll
  for (int j = 0; j < 12; ++j) { int c = j*64 + lane; orow[c] = f2bf((v[j]-mean)*rs*g[c] + b[c]); }
}

// ---------------------------------------------------------------- token assembly
__global__ __launch_bounds__(256) void assemble_kernel(
    const float* __restrict__ tok_emb, const float* __restrict__ pos_emb,
    const float* __restrict__ gpe, const int* __restrict__ text,
    const int* __restrict__ actions, const int* __restrict__ timesteps,
    const float* __restrict__ act_emb, const float* __restrict__ se,
    float* __restrict__ x)
{
  int idx = blockIdx.x * 256 + threadIdx.x;   // < 32*383*768 = 9,412,608
  if (idx >= 12256 * 768) return;
  int c  = idx % 768;
  int bt = idx / 768;
  int t  = bt % 383;
  int b  = bt / 383;
  float pos = gpe[(size_t)timesteps[b]*768 + c] + pos_emb[t*768 + c];
  float e;
  if (t < 128) {
    e = tok_emb[(size_t)text[b*128 + t]*768 + c];
  } else {
    int r = t - 128;
    if ((r & 1) == 0) e = se[((size_t)b*128 + (r >> 1))*768 + c];
    else              e = tanhf(act_emb[actions[b*128 + ((r+1) >> 1)]*768 + c]);
  }
  x[idx] = e + pos;
}

// ---------------------------------------------------------------- attention: MFMA, trimmed staging (static segments)
__global__ __launch_bounds__(256, 1) void attn_mfma(const bf16* __restrict__ qkv, bf16* __restrict__ yb)
{
  __shared__ __align__(16) unsigned short Ks[384*72];   // K  [t][d], pad 72  (55,296 B)
  __shared__ __align__(16) unsigned short VT[64*392];   // V^T[d][t], pad 392 (50,176 B)
  __shared__ __align__(16) unsigned short Pl[64*392];   // P  [row][t], pad   (50,176 B)
  const int tid = threadIdx.x, wave = tid >> 6, lane = tid & 63;
  const int l16 = lane & 15, l4 = lane >> 4;
  const int b = blockIdx.x / 12, hh = blockIdx.x % 12;
  const int rb = blockIdx.y;                            // 0..5, rows rb*64..rb*64+63
  const size_t qbase = ((size_t)b * 383) * 2304 + (size_t)hh * 64;
  const size_t kbase = qbase + 768;
  const size_t vbase = qbase + 1536;
  const size_t ybase = ((size_t)b * 383) * 768 + (size_t)hh * 64;
  const unsigned short* qk = (const unsigned short*)qkv;

  const int tlim = (rb == 5) ? 383 : (rb*64 + 64);      // keys needed by this row block
  #pragma unroll
  for (int seg = 0; seg < 6; ++seg) {
    if (seg <= rb) {                                    // wave-uniform guard; inner loops compile-time
      #pragma unroll
      for (int it = 0; it < 4; ++it) {
        int f = it*256 + tid;                           // 0..1023 within segment
        if (seg < 5 || f < 1008) {                      // seg 5 has 63 rows (t=383 excluded)
          int t = seg*64 + (f >> 4), d4 = (f & 15) << 2;
          u16x4 kv = *(const u16x4*)(qk + kbase + (size_t)t*2304 + d4);
          u16x4 vv = *(const u16x4*)(qk + vbase + (size_t)t*2304 + d4);
          *(u16x4*)(Ks + t*72 + d4) = kv;
          VT[(d4+0)*392 + t] = vv[0];
          VT[(d4+1)*392 + t] = vv[1];
          VT[(d4+2)*392 + t] = vv[2];
          VT[(d4+3)*392 + t] = vv[3];
        }
      }
    }
  }
  // zero-fill VT tail t in [tlim, 384) so PV's P=0 x VT contributions are exact 0
  if (rb == 5) {
    if (tid < 64) VT[tid*392 + 383] = 0;
  } else {
    const int cnt = (384 - tlim) >> 2;
    const int total = 64 * cnt;
    u16x4 z4 = {0, 0, 0, 0};
    for (int f = tid; f < total; f += 256) {
      int d = f / cnt, j = f - d*cnt;
      *(u16x4*)(VT + d*392 + tlim + j*4) = z4;
    }
  }
  __syncthreads();

  const int qrow0 = rb*64 + wave*16;
  short8 qa[2];
  #pragma unroll
  for (int kk = 0; kk < 2; ++kk)
    qa[kk] = *(const short8*)(qk + qbase + (size_t)(qrow0 + l16)*2304 + kk*32 + l4*8);

  f32x4 sfr[24];
  #pragma unroll
  for (int kt = 0; kt < 24; ++kt) { f32x4 z = {0.f,0.f,0.f,0.f}; sfr[kt] = z; }
  #pragma unroll
  for (int kk = 0; kk < 2; ++kk)
    #pragma unroll
    for (int kt = 0; kt < 24; ++kt) {
      short8 kf = *(const short8*)(Ks + (kt*16 + l16)*72 + kk*32 + l4*8);
      sfr[kt] = __builtin_amdgcn_mfma_f32_16x16x32_bf16(qa[kk], kf, sfr[kt], 0, 0, 0);
    }

  float linv[4];
  #pragma unroll
  for (int r = 0; r < 4; ++r) {
    const int gr = qrow0 + l4*4 + r;
    float mx = -1e30f;
    #pragma unroll
    for (int kt = 0; kt < 24; ++kt) {
      int gk = kt*16 + l16;
      float s = sfr[kt][r] * 0.125f;
      s = (gk <= gr) ? s : -1e30f;
      sfr[kt][r] = s;
      mx = fmaxf(mx, s);
    }
    #pragma unroll
    for (int off = 8; off; off >>= 1) mx = fmaxf(mx, __shfl_xor(mx, off));
    float ls = 0.f;
    #pragma unroll
    for (int kt = 0; kt < 24; ++kt) {
      float p = __expf(sfr[kt][r] - mx);
      ls += p;
      ((bf16*)Pl)[(wave*16 + l4*4 + r)*392 + kt*16 + l16] = f2bf(p);
    }
    #pragma unroll
    for (int off = 8; off; off >>= 1) ls += __shfl_xor(ls, off);
    linv[r] = 1.0f / ls;
  }

  f32x4 acc[4];
  #pragma unroll
  for (int j = 0; j < 4; ++j) { f32x4 z = {0.f,0.f,0.f,0.f}; acc[j] = z; }
  #pragma unroll
  for (int kt2 = 0; kt2 < 12; ++kt2) {
    short8 pf = *(const short8*)(Pl + (wave*16 + l16)*392 + kt2*32 + l4*8);
    #pragma unroll
    for (int j = 0; j < 4; ++j) {
      short8 vf = *(const short8*)(VT + (j*16 + l16)*392 + kt2*32 + l4*8);
      acc[j] = __builtin_amdgcn_mfma_f32_16x16x32_bf16(pf, vf, acc[j], 0, 0, 0);
    }
  }
  #pragma unroll
  for (int j = 0; j < 4; ++j)
    #pragma unroll
    for (int r = 0; r < 4; ++r) {
      int gr = qrow0 + l4*4 + r;
      if (gr < 383)
        yb[ybase + (size_t)gr*768 + j*16 + l16] = f2bf(acc[j][r] * linv[r]);
    }
}

// ---------------------------------------------------------------- head: logits for selected tokens
__global__ __launch_bounds__(256) void head_kernel(const bf16* __restrict__ af,
    const bf16* __restrict__ hw, float* __restrict__ out)
{
  int wave = threadIdx.x >> 6, lane = threadIdx.x & 63;
  int token = blockIdx.x * 4 + wave;       // < 4096
  int b = token >> 7, s = token & 127;
  size_t row = (size_t)b * 383 + 128 + 2*s;
  float av[12];
  #pragma unroll
  for (int j = 0; j < 12; ++j) av[j] = bf2f(af[row*768 + j*64 + lane]);
  for (int vv = 0; vv < 18; ++vv) {
    float p = 0.f;
    #pragma unroll
    for (int j = 0; j < 12; ++j) p = fmaf(av[j], bf2f(hw[vv*768 + j*64 + lane]), p);
    #pragma unroll
    for (int off = 32; off; off >>= 1) p += __shfl_xor(p, off);
    if (lane == 0) out[(size_t)token*18 + vv] = p;
  }
}

// ---------------------------------------------------------------- launch
extern "C" void kernel_launch(void* const* d_in, const int* in_sizes, int n_in,
                              void* d_out, int out_size, void* d_ws, size_t ws_size,
                              hipStream_t stream)
{
  const float* states   = (const float*)d_in[0];
  const int*   actions  = (const int*)d_in[1];
  const int*   text     = (const int*)d_in[2];
  const int*   timestep = (const int*)d_in[3];
  const float* tok_emb  = (const float*)d_in[4];
  const float* pos_emb  = (const float*)d_in[5];
  const float* gpe      = (const float*)d_in[6];
  const float* conv_w1  = (const float*)d_in[7];
  const float* conv_b1  = (const float*)d_in[8];
  const float* conv_w2  = (const float*)d_in[9];
  const float* conv_b2  = (const float*)d_in[10];
  const float* conv_w3  = (const float*)d_in[11];
  const float* conv_b3  = (const float*)d_in[12];
  const float* enc_w    = (const float*)d_in[13];
  const float* enc_b    = (const float*)d_in[14];
  const float* act_emb  = (const float*)d_in[15];
  const float* ln1_g    = (const float*)d_in[16];
  const float* ln1_b    = (const float*)d_in[17];
  const float* ln2_g    = (const float*)d_in[18];
  const float* ln2_b    = (const float*)d_in[19];
  const float* Wq       = (const float*)d_in[20];
  const float* bq       = (const float*)d_in[21];
  const float* Wk       = (const float*)d_in[22];
  const float* bk       = (const float*)d_in[23];
  const float* Wv       = (const float*)d_in[24];
  const float* bv       = (const float*)d_in[25];
  const float* Wo       = (const float*)d_in[26];
  const float* bo       = (const float*)d_in[27];
  const float* m1w      = (const float*)d_in[28];
  const float* m1b      = (const float*)d_in[29];
  const float* m2w      = (const float*)d_in[30];
  const float* m2b      = (const float*)d_in[31];
  const float* lnf_g    = (const float*)d_in[32];
  const float* lnf_b    = (const float*)d_in[33];
  const float* head_w   = (const float*)d_in[34];

  // ---- workspace layout (total 136,937,472 B ~ 137 MB) ----
  char* ws = (char*)d_ws;
  bf16*  wbuf = (bf16*)(ws);                          // 0 .. 4,816,896 (weight staging)
  float* qkvb = (float*)(ws + 4807680);               // 9,216 B bias concat (tail of wbuf region)
  // conv phase (im2col + GEMM, 8 chunks x 512 images):
  char*  A0p  = ws + 4816896;                         // arena base
  bf16*  c3f  = (bf16*)(A0p);                         // [4096*49][64] rows img*49+pos : 25,690,112 B
  char*  S0   = A0p + 25690112;                       // chunk scratch
  bf16*  P1c  = (bf16*)(S0);                          // 26,214,400
  bf16*  C1c  = (bf16*)(S0 + 26214400);               // 13,107,200
  bf16*  P2c  = (bf16*)(S0 + 39321600);               // 42,467,328
  bf16*  C2c  = (bf16*)(S0 + 81788928);               //  5,308,416
  bf16*  P3c  = (bf16*)(S0);                          // 28,901,376 (P1c/C1c dead)
  float* se   = (float*)(A0p + 119537664);            // 12,582,912 (persists to assemble)
  // transformer phase:
  float* x    = (float*)(A0p);                        // 12256*768 f32 = 37,650,432
  bf16*  a    = (bf16*)(ws + 42467328);               // 12288*768 bf16
  char*  R    = ws + 61341696;                        // 75,497,472 shared region
  bf16*  qkv  = (bf16*)(R);                           // 12256*2304 bf16 = 56,512,512
  bf16*  y    = (bf16*)(R + 56623104);                // 12288*768 bf16 = 18,874,368
  bf16*  h    = (bf16*)(R);                           // MLP phase (after qkv consumed)

  // conv weights -> bf16 (w1@0: 2048, w2@2048: 32768, w3@34816: 36864)
  cvt_kernel<<<8,   256, 0, stream>>>(conv_w1, wbuf,          2048);
  cvt_kernel<<<128, 256, 0, stream>>>(conv_w2, wbuf + 2048,  32768);
  cvt_kernel<<<144, 256, 0, stream>>>(conv_w3, wbuf + 34816, 36864);

  for (int c = 0; c < 8; ++c) {
    const float* st = states + (size_t)c * 512 * 7056;
    im2col1<<<51200, 256, 0, stream>>>(st, P1c);
    gemm_bt64<3,0><<<dim3(1600,1), 256, 0, stream>>>(P1c, wbuf,         conv_b1, C1c, 204800, 32, 64);
    im2col2<<<82944, 256, 0, stream>>>(C1c, P2c);
    gemm_bt64<3,0><<<dim3(324,1),  256, 0, stream>>>(P2c, wbuf + 2048,  conv_b2, C2c, 41472, 64, 512);
    im2col3<<<56448, 256, 0, stream>>>(C2c, P3c);
    gemm_bt64<3,0><<<dim3(196,1),  256, 0, stream>>>(P3c, wbuf + 34816, conv_b3,
                                                     c3f + (size_t)c * 25088 * 64, 25088, 64, 576);
  }

  // se = tanh(c3f @ enc_w'^T + enc_b)
  cvt_enc<<<9408, 256, 0, stream>>>(enc_w, wbuf);
  gemm_bt64<1,1><<<dim3(32, 12), 256, 0, stream>>>(c3f, wbuf, enc_b, se, 4096, 768, 3136);
  assemble_kernel<<<36768, 256, 0, stream>>>(tok_emb, pos_emb, gpe, text, actions, timestep, act_emb, se, x);

  for (int l = 0; l < 12; ++l) {
    ln_kernel<<<3064, 256, 0, stream>>>(x, ln1_g + l*768, ln1_b + l*768, a, 12256);
    cvt_qkv<<<6921, 256, 0, stream>>>(Wq + (size_t)l*589824, Wk + (size_t)l*589824,
                                      Wv + (size_t)l*589824, bq + l*768, bk + l*768, bv + l*768,
                                      wbuf, qkvb);
    gemm_bt192<0,0><<<dim3(96, 12), 256, 0, stream>>>(a, wbuf, qkvb, qkv, 12256, 2304, 768);
    attn_mfma<<<dim3(384, 6), 256, 0, stream>>>(qkv, y);
    cvt_kernel<<<2304, 256, 0, stream>>>(Wo + (size_t)l*589824, wbuf, 589824);
    gemm_bt64<0,2><<<dim3(96, 12), 256, 0, stream>>>(y, wbuf, bo + l*768, x, 12256, 768, 768);
    ln_kernel<<<3064, 256, 0, stream>>>(x, ln2_g + l*768, ln2_b + l*768, a, 12256);
    cvt_kernel<<<9216, 256, 0, stream>>>(m1w + (size_t)l*2359296, wbuf, 2359296);
    gemm_bt192<2,0><<<dim3(96, 16), 256, 0, stream>>>(a, wbuf, m1b + l*3072, h, 12256, 3072, 768);
    cvt_kernel<<<9216, 256, 0, stream>>>(m2w + (size_t)l*2359296, wbuf, 2359296);
    gemm_bt64<0,2><<<dim3(96, 12), 256, 0, stream>>>(h, wbuf, m2b + l*768, x, 12256, 768, 3072);
  }

  ln_kernel<<<3064, 256, 0, stream>>>(x, lnf_g, lnf_b, a, 12256);
  cvt_kernel<<<54, 256, 0, stream>>>(head_w, wbuf, 13824);
  head_kernel<<<1024, 256, 0, stream>>>(a, wbuf, (float*)d_out);
}

// Round 23
// 6970.789 us; speedup vs baseline: 1.3805x; 1.3805x over previous
//
#include <hip/hip_runtime.h>
#include <hip/hip_bf16.h>
#include <math.h>

using bf16 = __hip_bfloat16;
typedef __attribute__((ext_vector_type(8))) short short8;
typedef __attribute__((ext_vector_type(4))) short s16x4;
typedef __attribute__((ext_vector_type(4))) float f32x4;
typedef __attribute__((ext_vector_type(4))) unsigned short u16x4;

#define DEVFN __device__ __forceinline__

DEVFN float bf2f(bf16 v) { return __bfloat162float(v); }
DEVFN bf16  f2bf(float v) { return __float2bfloat16(v); }
DEVFN short bfbits(float v) { bf16 h = __float2bfloat16(v); return *reinterpret_cast<short*>(&h); }

// ---------------------------------------------------------------- f32 -> bf16 (scalar, for odd shapes)
__global__ __launch_bounds__(256) void cvt_kernel(const float* __restrict__ in, bf16* __restrict__ out, int n)
{
  int i = blockIdx.x * 256 + threadIdx.x;
  if (i < n) out[i] = f2bf(in[i]);
}

// f32 -> bf16, 4-wide (n divisible by 4; n4 = n/4)
__global__ __launch_bounds__(256) void cvt_kernel4(const float* __restrict__ in, bf16* __restrict__ out, int n4)
{
  int i = blockIdx.x * 256 + threadIdx.x;
  if (i < n4) {
    float4 v = ((const float4*)in)[i];
    s16x4 o = { bfbits(v.x), bfbits(v.y), bfbits(v.z), bfbits(v.w) };
    *(s16x4*)(out + (size_t)i * 4) = o;
  }
}

// fused QKV weight+bias conversion, 4-wide. 442,368 weight-quads + 576 bias-quads.
__global__ __launch_bounds__(256) void cvt_qkv4(const float* __restrict__ wq,
    const float* __restrict__ wk, const float* __restrict__ wv,
    const float* __restrict__ bq, const float* __restrict__ bk, const float* __restrict__ bv,
    bf16* __restrict__ out, float* __restrict__ bout)
{
  int i = blockIdx.x * 256 + threadIdx.x;       // grid 1731 -> 443,136 >= 442,944
  if (i < 442368) {
    int e = i * 4;                              // segments are /4 so quads never straddle
    const float* src = (e < 589824) ? (wq + e)
                     : (e < 1179648) ? (wk + (e - 589824))
                     : (wv + (e - 1179648));
    float4 v = *(const float4*)src;
    s16x4 o = { bfbits(v.x), bfbits(v.y), bfbits(v.z), bfbits(v.w) };
    *(s16x4*)(out + (size_t)e) = o;
  } else if (i < 442944) {
    int j = (i - 442368) * 4;                   // 0..2300
    #pragma unroll
    for (int t = 0; t < 4; ++t) {
      int c = j + t;
      bout[c] = (c < 768) ? bq[c] : (c < 1536) ? bk[c - 768] : bv[c - 1536];
    }
  }
}

// enc_w column permutation: out[n][pos*64+co] = in[n][co*49+pos]  (768 x 3136)
__global__ __launch_bounds__(256) void cvt_enc(const float* __restrict__ in, bf16* __restrict__ out)
{
  int i = blockIdx.x * 256 + threadIdx.x;       // 2,408,448 = 9408*256 exact
  int n = i / 3136, kp = i - n * 3136;
  int pos = kp >> 6, co = kp & 63;
  out[i] = f2bf(in[n * 3136 + co * 49 + pos]);
}

// ---------------------------------------------------------------- im2col kernels (per 512-image chunk)
__global__ __launch_bounds__(256) void im2col1(const float* __restrict__ states, bf16* __restrict__ P1)
{
  int idx = blockIdx.x * 256 + threadIdx.x;     // 13,107,200 = 51,200*256 exact
  int row = idx >> 6, k = idx & 63;
  int imgL = row / 400, pos = row - imgL * 400;
  int oy = pos / 20, ox = pos - oy * 20;
  int ky = k >> 3, kx = k & 7;
  float v = states[(size_t)imgL * 7056 + (oy * 4 + ky) * 84 + ox * 4 + kx] * (1.0f / 255.0f);
  P1[idx] = f2bf(v);
}

__global__ __launch_bounds__(256) void im2col2(const bf16* __restrict__ C1, bf16* __restrict__ P2)
{
  int idx = blockIdx.x * 256 + threadIdx.x;     // 21,233,664 = 82,944*256 exact
  int row = idx >> 9, k = idx & 511;
  int imgL = row / 81, pos = row - imgL * 81;
  int oy = pos / 9, ox = pos - oy * 9;
  int ci = k >> 4, r = k & 15, ky = r >> 2, kx = r & 3;
  P2[idx] = C1[((size_t)imgL * 400 + (oy * 2 + ky) * 20 + ox * 2 + kx) * 32 + ci];
}

__global__ __launch_bounds__(256) void im2col3(const bf16* __restrict__ C2, bf16* __restrict__ P3)
{
  int idx = blockIdx.x * 256 + threadIdx.x;     // 14,450,688 = 56,448*256 exact
  int row = idx / 576, k = idx - row * 576;
  int imgL = row / 49, pos = row - imgL * 49;
  int oy = pos / 7, ox = pos - oy * 7;
  int ci = k / 9, r = k - ci * 9;
  int ky = r / 3, kx = r - ky * 3;
  P3[idx] = C2[((size_t)imgL * 81 + (oy + ky) * 9 + ox + kx) * 64 + ci];
}

// ---------------------------------------------------------------- MFMA GEMM, 128x128 tile (R16-verified)
// out = act(A @ W^T + bias). ACT: 0 none, 1 tanh, 2 gelu, 3 relu. OUTMODE: 0 bf16, 1 f32, 2 f32 +=
template<int ACT, int OUTMODE>
__global__ __launch_bounds__(256) void gemm_bt(
    const bf16* __restrict__ A, const bf16* __restrict__ W,
    const float* __restrict__ bias, void* __restrict__ outp,
    int M, int N, int K)
{
  __shared__ bf16 As[128*64];
  __shared__ bf16 Bs[128*64];
  const int tid = threadIdx.x;
  const int lane = tid & 63, wave = tid >> 6;
  const int m0 = blockIdx.x * 128, n0 = blockIdx.y * 128;
  const int wm = (wave >> 1) * 64, wn = (wave & 1) * 64;
  const int l16 = lane & 15, l4 = lane >> 4;
  f32x4 acc[4][4];
  #pragma unroll
  for (int i = 0; i < 4; ++i)
    #pragma unroll
    for (int j = 0; j < 4; ++j) { f32x4 z = {0.f,0.f,0.f,0.f}; acc[i][j] = z; }

  for (int k0 = 0; k0 < K; k0 += 64) {
    __syncthreads();
    #pragma unroll
    for (int it = 0; it < 4; ++it) {
      int f = it*256 + tid;
      int row = f >> 3;
      int col = (f & 7) << 3;
      const bf16* ga = A + (size_t)(m0 + row) * K + k0 + col;
      const bf16* gb = W + (size_t)(n0 + row) * K + k0 + col;
      __builtin_amdgcn_global_load_lds((const __attribute__((address_space(1))) void*)ga,
                                       (__attribute__((address_space(3))) void*)(As + f*8), 16, 0, 0);
      __builtin_amdgcn_global_load_lds((const __attribute__((address_space(1))) void*)gb,
                                       (__attribute__((address_space(3))) void*)(Bs + f*8), 16, 0, 0);
    }
    __syncthreads();
    #pragma unroll
    for (int kk = 0; kk < 2; ++kk) {
      short8 af[4], bfr[4];
      #pragma unroll
      for (int i = 0; i < 4; ++i) af[i]  = *(const short8*)(As + (wm + i*16 + l16)*64 + kk*32 + l4*8);
      #pragma unroll
      for (int j = 0; j < 4; ++j) bfr[j] = *(const short8*)(Bs + (wn + j*16 + l16)*64 + kk*32 + l4*8);
      #pragma unroll
      for (int i = 0; i < 4; ++i)
        #pragma unroll
        for (int j = 0; j < 4; ++j)
          acc[i][j] = __builtin_amdgcn_mfma_f32_16x16x32_bf16(af[i], bfr[j], acc[i][j], 0, 0, 0);
    }
  }
  #pragma unroll
  for (int i = 0; i < 4; ++i)
    #pragma unroll
    for (int j = 0; j < 4; ++j)
      #pragma unroll
      for (int r = 0; r < 4; ++r) {
        int grow = m0 + wm + i*16 + l4*4 + r;
        int gcol = n0 + wn + j*16 + l16;
        if (grow < M && gcol < N) {
          float v = acc[i][j][r] + bias[gcol];
          if (ACT == 1) v = tanhf(v);
          else if (ACT == 2) v = 0.5f * v * (1.0f + erff(v * 0.70710678118654752f));
          else if (ACT == 3) v = fmaxf(v, 0.0f);
          size_t idx = (size_t)grow * N + gcol;
          if (OUTMODE == 0)      ((bf16*)outp)[idx] = f2bf(v);
          else if (OUTMODE == 1) ((float*)outp)[idx] = v;
          else                   ((float*)outp)[idx] += v;
        }
      }
}

// ---------------------------------------------------------------- MFMA GEMM, 128x64 tile (more blocks/CU)
template<int ACT, int OUTMODE>
__global__ __launch_bounds__(256) void gemm_bt64(
    const bf16* __restrict__ A, const bf16* __restrict__ W,
    const float* __restrict__ bias, void* __restrict__ outp,
    int M, int N, int K)
{
  __shared__ bf16 As[128*64];
  __shared__ bf16 Bs[64*64];
  const int tid = threadIdx.x;
  const int lane = tid & 63, wave = tid >> 6;
  const int m0 = blockIdx.x * 128, n0 = blockIdx.y * 64;
  const int wm = wave * 32;
  const int l16 = lane & 15, l4 = lane >> 4;
  f32x4 acc[2][4];
  #pragma unroll
  for (int i = 0; i < 2; ++i)
    #pragma unroll
    for (int j = 0; j < 4; ++j) { f32x4 z = {0.f,0.f,0.f,0.f}; acc[i][j] = z; }

  for (int k0 = 0; k0 < K; k0 += 64) {
    __syncthreads();
    #pragma unroll
    for (int it = 0; it < 4; ++it) {          // A: 128x64 = 1024 slots of 8
      int f = it*256 + tid;
      int row = f >> 3, col = (f & 7) << 3;
      const bf16* ga = A + (size_t)(m0 + row) * K + k0 + col;
      __builtin_amdgcn_global_load_lds((const __attribute__((address_space(1))) void*)ga,
                                       (__attribute__((address_space(3))) void*)(As + f*8), 16, 0, 0);
    }
    #pragma unroll
    for (int it = 0; it < 2; ++it) {          // B: 64x64 = 512 slots of 8
      int f = it*256 + tid;
      int row = f >> 3, col = (f & 7) << 3;
      const bf16* gb = W + (size_t)(n0 + row) * K + k0 + col;
      __builtin_amdgcn_global_load_lds((const __attribute__((address_space(1))) void*)gb,
                                       (__attribute__((address_space(3))) void*)(Bs + f*8), 16, 0, 0);
    }
    __syncthreads();
    #pragma unroll
    for (int kk = 0; kk < 2; ++kk) {
      short8 af[2], bfr[4];
      #pragma unroll
      for (int i = 0; i < 2; ++i) af[i]  = *(const short8*)(As + (wm + i*16 + l16)*64 + kk*32 + l4*8);
      #pragma unroll
      for (int j = 0; j < 4; ++j) bfr[j] = *(const short8*)(Bs + (j*16 + l16)*64 + kk*32 + l4*8);
      #pragma unroll
      for (int i = 0; i < 2; ++i)
        #pragma unroll
        for (int j = 0; j < 4; ++j)
          acc[i][j] = __builtin_amdgcn_mfma_f32_16x16x32_bf16(af[i], bfr[j], acc[i][j], 0, 0, 0);
    }
  }
  #pragma unroll
  for (int i = 0; i < 2; ++i)
    #pragma unroll
    for (int j = 0; j < 4; ++j)
      #pragma unroll
      for (int r = 0; r < 4; ++r) {
        int grow = m0 + wm + i*16 + l4*4 + r;
        int gcol = n0 + j*16 + l16;
        if (grow < M && gcol < N) {
          float v = acc[i][j][r] + bias[gcol];
          if (ACT == 1) v = tanhf(v);
          else if (ACT == 2) v = 0.5f * v * (1.0f + erff(v * 0.70710678118654752f));
          else if (ACT == 3) v = fmaxf(v, 0.0f);
          size_t idx = (size_t)grow * N + gcol;
          if (OUTMODE == 0)      ((bf16*)outp)[idx] = f2bf(v);
          else if (OUTMODE == 1) ((float*)outp)[idx] = v;
          else                   ((float*)outp)[idx] += v;
        }
      }
}

// ---------------------------------------------------------------- LayerNorm -> bf16
__global__ __launch_bounds__(256) void ln_kernel(const float* __restrict__ x,
    const float* __restrict__ g, const float* __restrict__ b,
    bf16* __restrict__ out, int rows)
{
  int wave = threadIdx.x >> 6, lane = threadIdx.x & 63;
  int row = blockIdx.x * 4 + wave;
  if (row >= rows) return;
  const float* xr = x + (size_t)row * 768;
  float v[12]; float s = 0.f, s2 = 0.f;
  #pragma unroll
  for (int j = 0; j < 12; ++j) { float t = xr[j*64 + lane]; v[j] = t; s += t; s2 = fmaf(t, t, s2); }
  #pragma unroll
  for (int off = 32; off; off >>= 1) { s += __shfl_xor(s, off); s2 += __shfl_xor(s2, off); }
  float mean = s * (1.0f/768.0f);
  float var  = s2 * (1.0f/768.0f) - mean*mean;
  float rs   = rsqrtf(var + 1e-5f);
  bf16* orow = out + (size_t)row * 768;
  #pragma unroll
  for (int j = 0; j < 12; ++j) { int c = j*64 + lane; orow[c] = f2bf((v[j]-mean)*rs*g[c] + b[c]); }
}

// ---------------------------------------------------------------- token assembly
__global__ __launch_bounds__(256) void assemble_kernel(
    const float* __restrict__ tok_emb, const float* __restrict__ pos_emb,
    const float* __restrict__ gpe, const int* __restrict__ text,
    const int* __restrict__ actions, const int* __restrict__ timesteps,
    const float* __restrict__ act_emb, const float* __restrict__ se,
    float* __restrict__ x)
{
  int idx = blockIdx.x * 256 + threadIdx.x;   // < 32*383*768 = 9,412,608
  if (idx >= 12256 * 768) return;
  int c  = idx % 768;
  int bt = idx / 768;
  int t  = bt % 383;
  int b  = bt / 383;
  float pos = gpe[(size_t)timesteps[b]*768 + c] + pos_emb[t*768 + c];
  float e;
  if (t < 128) {
    e = tok_emb[(size_t)text[b*128 + t]*768 + c];
  } else {
    int r = t - 128;
    if ((r & 1) == 0) e = se[((size_t)b*128 + (r >> 1))*768 + c];
    else              e = tanhf(act_emb[actions[b*128 + ((r+1) >> 1)]*768 + c]);
  }
  x[idx] = e + pos;
}

// ---------------------------------------------------------------- attention: MFMA, trimmed staging (static segments)
__global__ __launch_bounds__(256, 1) void attn_mfma(const bf16* __restrict__ qkv, bf16* __restrict__ yb)
{
  __shared__ __align__(16) unsigned short Ks[384*72];   // K  [t][d], pad 72  (55,296 B)
  __shared__ __align__(16) unsigned short VT[64*392];   // V^T[d][t], pad 392 (50,176 B)
  __shared__ __align__(16) unsigned short Pl[64*392];   // P  [row][t], pad   (50,176 B)
  const int tid = threadIdx.x, wave = tid >> 6, lane = tid & 63;
  const int l16 = lane & 15, l4 = lane >> 4;
  const int b = blockIdx.x / 12, hh = blockIdx.x % 12;
  const int rb = blockIdx.y;                            // 0..5, rows rb*64..rb*64+63
  const size_t qbase = ((size_t)b * 383) * 2304 + (size_t)hh * 64;
  const size_t kbase = qbase + 768;
  const size_t vbase = qbase + 1536;
  const size_t ybase = ((size_t)b * 383) * 768 + (size_t)hh * 64;
  const unsigned short* qk = (const unsigned short*)qkv;

  const int tlim = (rb == 5) ? 383 : (rb*64 + 64);      // keys needed by this row block
  #pragma unroll
  for (int seg = 0; seg < 6; ++seg) {
    if (seg <= rb) {                                    // wave-uniform guard; inner loops compile-time
      #pragma unroll
      for (int it = 0; it < 4; ++it) {
        int f = it*256 + tid;                           // 0..1023 within segment
        if (seg < 5 || f < 1008) {                      // seg 5 has 63 rows (t=383 excluded)
          int t = seg*64 + (f >> 4), d4 = (f & 15) << 2;
          u16x4 kv = *(const u16x4*)(qk + kbase + (size_t)t*2304 + d4);
          u16x4 vv = *(const u16x4*)(qk + vbase + (size_t)t*2304 + d4);
          *(u16x4*)(Ks + t*72 + d4) = kv;
          VT[(d4+0)*392 + t] = vv[0];
          VT[(d4+1)*392 + t] = vv[1];
          VT[(d4+2)*392 + t] = vv[2];
          VT[(d4+3)*392 + t] = vv[3];
        }
      }
    }
  }
  // zero-fill VT tail t in [tlim, 384) so PV's P=0 x VT contributions are exact 0
  if (rb == 5) {
    if (tid < 64) VT[tid*392 + 383] = 0;
  } else {
    const int cnt = (384 - tlim) >> 2;
    const int total = 64 * cnt;
    u16x4 z4 = {0, 0, 0, 0};
    for (int f = tid; f < total; f += 256) {
      int d = f / cnt, j = f - d*cnt;
      *(u16x4*)(VT + d*392 + tlim + j*4) = z4;
    }
  }
  __syncthreads();

  const int qrow0 = rb*64 + wave*16;
  short8 qa[2];
  #pragma unroll
  for (int kk = 0; kk < 2; ++kk)
    qa[kk] = *(const short8*)(qk + qbase + (size_t)(qrow0 + l16)*2304 + kk*32 + l4*8);

  f32x4 sfr[24];
  #pragma unroll
  for (int kt = 0; kt < 24; ++kt) { f32x4 z = {0.f,0.f,0.f,0.f}; sfr[kt] = z; }
  #pragma unroll
  for (int kk = 0; kk < 2; ++kk)
    #pragma unroll
    for (int kt = 0; kt < 24; ++kt) {
      short8 kf = *(const short8*)(Ks + (kt*16 + l16)*72 + kk*32 + l4*8);
      sfr[kt] = __builtin_amdgcn_mfma_f32_16x16x32_bf16(qa[kk], kf, sfr[kt], 0, 0, 0);
    }

  float linv[4];
  #pragma unroll
  for (int r = 0; r < 4; ++r) {
    const int gr = qrow0 + l4*4 + r;
    float mx = -1e30f;
    #pragma unroll
    for (int kt = 0; kt < 24; ++kt) {
      int gk = kt*16 + l16;
      float s = sfr[kt][r] * 0.125f;
      s = (gk <= gr) ? s : -1e30f;
      sfr[kt][r] = s;
      mx = fmaxf(mx, s);
    }
    #pragma unroll
    for (int off = 8; off; off >>= 1) mx = fmaxf(mx, __shfl_xor(mx, off));
    float ls = 0.f;
    #pragma unroll
    for (int kt = 0; kt < 24; ++kt) {
      float p = __expf(sfr[kt][r] - mx);
      ls += p;
      ((bf16*)Pl)[(wave*16 + l4*4 + r)*392 + kt*16 + l16] = f2bf(p);
    }
    #pragma unroll
    for (int off = 8; off; off >>= 1) ls += __shfl_xor(ls, off);
    linv[r] = 1.0f / ls;
  }

  f32x4 acc[4];
  #pragma unroll
  for (int j = 0; j < 4; ++j) { f32x4 z = {0.f,0.f,0.f,0.f}; acc[j] = z; }
  #pragma unroll
  for (int kt2 = 0; kt2 < 12; ++kt2) {
    short8 pf = *(const short8*)(Pl + (wave*16 + l16)*392 + kt2*32 + l4*8);
    #pragma unroll
    for (int j = 0; j < 4; ++j) {
      short8 vf = *(const short8*)(VT + (j*16 + l16)*392 + kt2*32 + l4*8);
      acc[j] = __builtin_amdgcn_mfma_f32_16x16x32_bf16(pf, vf, acc[j], 0, 0, 0);
    }
  }
  #pragma unroll
  for (int j = 0; j < 4; ++j)
    #pragma unroll
    for (int r = 0; r < 4; ++r) {
      int gr = qrow0 + l4*4 + r;
      if (gr < 383)
        yb[ybase + (size_t)gr*768 + j*16 + l16] = f2bf(acc[j][r] * linv[r]);
    }
}

// ---------------------------------------------------------------- head: logits for selected tokens
__global__ __launch_bounds__(256) void head_kernel(const bf16* __restrict__ af,
    const bf16* __restrict__ hw, float* __restrict__ out)
{
  int wave = threadIdx.x >> 6, lane = threadIdx.x & 63;
  int token = blockIdx.x * 4 + wave;       // < 4096
  int b = token >> 7, s = token & 127;
  size_t row = (size_t)b * 383 + 128 + 2*s;
  float av[12];
  #pragma unroll
  for (int j = 0; j < 12; ++j) av[j] = bf2f(af[row*768 + j*64 + lane]);
  for (int vv = 0; vv < 18; ++vv) {
    float p = 0.f;
    #pragma unroll
    for (int j = 0; j < 12; ++j) p = fmaf(av[j], bf2f(hw[vv*768 + j*64 + lane]), p);
    #pragma unroll
    for (int off = 32; off; off >>= 1) p += __shfl_xor(p, off);
    if (lane == 0) out[(size_t)token*18 + vv] = p;
  }
}

// ---------------------------------------------------------------- launch
extern "C" void kernel_launch(void* const* d_in, const int* in_sizes, int n_in,
                              void* d_out, int out_size, void* d_ws, size_t ws_size,
                              hipStream_t stream)
{
  const float* states   = (const float*)d_in[0];
  const int*   actions  = (const int*)d_in[1];
  const int*   text     = (const int*)d_in[2];
  const int*   timestep = (const int*)d_in[3];
  const float* tok_emb  = (const float*)d_in[4];
  const float* pos_emb  = (const float*)d_in[5];
  const float* gpe      = (const float*)d_in[6];
  const float* conv_w1  = (const float*)d_in[7];
  const float* conv_b1  = (const float*)d_in[8];
  const float* conv_w2  = (const float*)d_in[9];
  const float* conv_b2  = (const float*)d_in[10];
  const float* conv_w3  = (const float*)d_in[11];
  const float* conv_b3  = (const float*)d_in[12];
  const float* enc_w    = (const float*)d_in[13];
  const float* enc_b    = (const float*)d_in[14];
  const float* act_emb  = (const float*)d_in[15];
  const float* ln1_g    = (const float*)d_in[16];
  const float* ln1_b    = (const float*)d_in[17];
  const float* ln2_g    = (const float*)d_in[18];
  const float* ln2_b    = (const float*)d_in[19];
  const float* Wq       = (const float*)d_in[20];
  const float* bq       = (const float*)d_in[21];
  const float* Wk       = (const float*)d_in[22];
  const float* bk       = (const float*)d_in[23];
  const float* Wv       = (const float*)d_in[24];
  const float* bv       = (const float*)d_in[25];
  const float* Wo       = (const float*)d_in[26];
  const float* bo       = (const float*)d_in[27];
  const float* m1w      = (const float*)d_in[28];
  const float* m1b      = (const float*)d_in[29];
  const float* m2w      = (const float*)d_in[30];
  const float* m2b      = (const float*)d_in[31];
  const float* lnf_g    = (const float*)d_in[32];
  const float* lnf_b    = (const float*)d_in[33];
  const float* head_w   = (const float*)d_in[34];

  // ---- workspace layout (total 136,937,472 B ~ 137 MB) ----
  char* ws = (char*)d_ws;
  bf16*  wbuf = (bf16*)(ws);                          // 0 .. 4,816,896 (weight staging)
  float* qkvb = (float*)(ws + 4807680);               // 9,216 B bias concat (tail of wbuf region)
  // conv phase (im2col + GEMM, 8 chunks x 512 images):
  char*  A0p  = ws + 4816896;                         // arena base
  bf16*  c3f  = (bf16*)(A0p);                         // [4096*49][64] rows img*49+pos : 25,690,112 B
  char*  S0   = A0p + 25690112;                       // chunk scratch
  bf16*  P1c  = (bf16*)(S0);                          // 26,214,400
  bf16*  C1c  = (bf16*)(S0 + 26214400);               // 13,107,200
  bf16*  P2c  = (bf16*)(S0 + 39321600);               // 42,467,328
  bf16*  C2c  = (bf16*)(S0 + 81788928);               //  5,308,416
  bf16*  P3c  = (bf16*)(S0);                          // 28,901,376 (P1c/C1c dead)
  float* se   = (float*)(A0p + 119537664);            // 12,582,912 (persists to assemble)
  // transformer phase:
  float* x    = (float*)(A0p);                        // 12256*768 f32 = 37,650,432
  bf16*  a    = (bf16*)(ws + 42467328);               // 12288*768 bf16
  char*  R    = ws + 61341696;                        // 75,497,472 shared region
  bf16*  qkv  = (bf16*)(R);                           // 12256*2304 bf16 = 56,512,512
  bf16*  y    = (bf16*)(R + 56623104);                // 12288*768 bf16 = 18,874,368
  bf16*  h    = (bf16*)(R);                           // MLP phase (after qkv consumed)

  // conv weights -> bf16 (w1@0: 2048, w2@2048: 32768, w3@34816: 36864), 4-wide
  cvt_kernel4<<<2,  256, 0, stream>>>(conv_w1, wbuf,          512);
  cvt_kernel4<<<32, 256, 0, stream>>>(conv_w2, wbuf + 2048,  8192);
  cvt_kernel4<<<36, 256, 0, stream>>>(conv_w3, wbuf + 34816, 9216);

  for (int c = 0; c < 8; ++c) {
    const float* st = states + (size_t)c * 512 * 7056;
    im2col1<<<51200, 256, 0, stream>>>(st, P1c);
    gemm_bt64<3,0><<<dim3(1600,1), 256, 0, stream>>>(P1c, wbuf,         conv_b1, C1c, 204800, 32, 64);
    im2col2<<<82944, 256, 0, stream>>>(C1c, P2c);
    gemm_bt64<3,0><<<dim3(324,1),  256, 0, stream>>>(P2c, wbuf + 2048,  conv_b2, C2c, 41472, 64, 512);
    im2col3<<<56448, 256, 0, stream>>>(C2c, P3c);
    gemm_bt64<3,0><<<dim3(196,1),  256, 0, stream>>>(P3c, wbuf + 34816, conv_b3,
                                                     c3f + (size_t)c * 25088 * 64, 25088, 64, 576);
  }

  // se = tanh(c3f @ enc_w'^T + enc_b)
  cvt_enc<<<9408, 256, 0, stream>>>(enc_w, wbuf);
  gemm_bt64<1,1><<<dim3(32, 12), 256, 0, stream>>>(c3f, wbuf, enc_b, se, 4096, 768, 3136);
  assemble_kernel<<<36768, 256, 0, stream>>>(tok_emb, pos_emb, gpe, text, actions, timestep, act_emb, se, x);

  for (int l = 0; l < 12; ++l) {
    ln_kernel<<<3064, 256, 0, stream>>>(x, ln1_g + l*768, ln1_b + l*768, a, 12256);
    cvt_qkv4<<<1731, 256, 0, stream>>>(Wq + (size_t)l*589824, Wk + (size_t)l*589824,
                                       Wv + (size_t)l*589824, bq + l*768, bk + l*768, bv + l*768,
                                       wbuf, qkvb);
    gemm_bt<0,0><<<dim3(96, 18), 256, 0, stream>>>(a, wbuf, qkvb, qkv, 12256, 2304, 768);
    attn_mfma<<<dim3(384, 6), 256, 0, stream>>>(qkv, y);
    cvt_kernel4<<<576, 256, 0, stream>>>(Wo + (size_t)l*589824, wbuf, 147456);
    gemm_bt64<0,2><<<dim3(96, 12), 256, 0, stream>>>(y, wbuf, bo + l*768, x, 12256, 768, 768);
    ln_kernel<<<3064, 256, 0, stream>>>(x, ln2_g + l*768, ln2_b + l*768, a, 12256);
    cvt_kernel4<<<2304, 256, 0, stream>>>(m1w + (size_t)l*2359296, wbuf, 589824);
    gemm_bt64<2,0><<<dim3(96, 48), 256, 0, stream>>>(a, wbuf, m1b + l*3072, h, 12256, 3072, 768);
    cvt_kernel4<<<2304, 256, 0, stream>>>(m2w + (size_t)l*2359296, wbuf, 589824);
    gemm_bt64<0,2><<<dim3(96, 12), 256, 0, stream>>>(h, wbuf, m2b + l*768, x, 12256, 768, 3072);
  }

  ln_kernel<<<3064, 256, 0, stream>>>(x, lnf_g, lnf_b, a, 12256);
  cvt_kernel4<<<14, 256, 0, stream>>>(head_w, wbuf, 3456);
  head_kernel<<<1024, 256, 0, stream>>>(a, wbuf, (float*)d_out);
}

// Round 24
// 6588.674 us; speedup vs baseline: 1.4606x; 1.0580x over previous
//
#include <hip/hip_runtime.h>
#include <hip/hip_bf16.h>
#include <math.h>

using bf16 = __hip_bfloat16;
typedef __attribute__((ext_vector_type(8))) short short8;
typedef __attribute__((ext_vector_type(4))) short s16x4;
typedef __attribute__((ext_vector_type(4))) float f32x4;
typedef __attribute__((ext_vector_type(4))) unsigned short u16x4;

#define DEVFN __device__ __forceinline__

DEVFN float bf2f(bf16 v) { return __bfloat162float(v); }
DEVFN bf16  f2bf(float v) { return __float2bfloat16(v); }
DEVFN short bfbits(float v) { bf16 h = __float2bfloat16(v); return *reinterpret_cast<short*>(&h); }

// ---------------------------------------------------------------- f32 -> bf16 (scalar, for odd shapes)
__global__ __launch_bounds__(256) void cvt_kernel(const float* __restrict__ in, bf16* __restrict__ out, int n)
{
  int i = blockIdx.x * 256 + threadIdx.x;
  if (i < n) out[i] = f2bf(in[i]);
}

// f32 -> bf16, 4-wide (n divisible by 4; n4 = n/4)
__global__ __launch_bounds__(256) void cvt_kernel4(const float* __restrict__ in, bf16* __restrict__ out, int n4)
{
  int i = blockIdx.x * 256 + threadIdx.x;
  if (i < n4) {
    float4 v = ((const float4*)in)[i];
    s16x4 o = { bfbits(v.x), bfbits(v.y), bfbits(v.z), bfbits(v.w) };
    *(s16x4*)(out + (size_t)i * 4) = o;
  }
}

// fused QKV weight+bias conversion, 4-wide. 442,368 weight-quads + 576 bias-quads.
__global__ __launch_bounds__(256) void cvt_qkv4(const float* __restrict__ wq,
    const float* __restrict__ wk, const float* __restrict__ wv,
    const float* __restrict__ bq, const float* __restrict__ bk, const float* __restrict__ bv,
    bf16* __restrict__ out, float* __restrict__ bout)
{
  int i = blockIdx.x * 256 + threadIdx.x;       // grid 1731 -> 443,136 >= 442,944
  if (i < 442368) {
    int e = i * 4;                              // segments are /4 so quads never straddle
    const float* src = (e < 589824) ? (wq + e)
                     : (e < 1179648) ? (wk + (e - 589824))
                     : (wv + (e - 1179648));
    float4 v = *(const float4*)src;
    s16x4 o = { bfbits(v.x), bfbits(v.y), bfbits(v.z), bfbits(v.w) };
    *(s16x4*)(out + (size_t)e) = o;
  } else if (i < 442944) {
    int j = (i - 442368) * 4;                   // 0..2300
    #pragma unroll
    for (int t = 0; t < 4; ++t) {
      int c = j + t;
      bout[c] = (c < 768) ? bq[c] : (c < 1536) ? bk[c - 768] : bv[c - 1536];
    }
  }
}

// enc_w column permutation: out[n][pos*64+co] = in[n][co*49+pos]  (768 x 3136)
__global__ __launch_bounds__(256) void cvt_enc(const float* __restrict__ in, bf16* __restrict__ out)
{
  int i = blockIdx.x * 256 + threadIdx.x;       // 2,408,448 = 9408*256 exact
  int n = i / 3136, kp = i - n * 3136;
  int pos = kp >> 6, co = kp & 63;
  out[i] = f2bf(in[n * 3136 + co * 49 + pos]);
}

// ---------------------------------------------------------------- im2col kernels (per 512-image chunk)
__global__ __launch_bounds__(256) void im2col1(const float* __restrict__ states, bf16* __restrict__ P1)
{
  int idx = blockIdx.x * 256 + threadIdx.x;     // 13,107,200 = 51,200*256 exact
  int row = idx >> 6, k = idx & 63;
  int imgL = row / 400, pos = row - imgL * 400;
  int oy = pos / 20, ox = pos - oy * 20;
  int ky = k >> 3, kx = k & 7;
  float v = states[(size_t)imgL * 7056 + (oy * 4 + ky) * 84 + ox * 4 + kx] * (1.0f / 255.0f);
  P1[idx] = f2bf(v);
}

__global__ __launch_bounds__(256) void im2col2(const bf16* __restrict__ C1, bf16* __restrict__ P2)
{
  int idx = blockIdx.x * 256 + threadIdx.x;     // 21,233,664 = 82,944*256 exact
  int row = idx >> 9, k = idx & 511;
  int imgL = row / 81, pos = row - imgL * 81;
  int oy = pos / 9, ox = pos - oy * 9;
  int ci = k >> 4, r = k & 15, ky = r >> 2, kx = r & 3;
  P2[idx] = C1[((size_t)imgL * 400 + (oy * 2 + ky) * 20 + ox * 2 + kx) * 32 + ci];
}

__global__ __launch_bounds__(256) void im2col3(const bf16* __restrict__ C2, bf16* __restrict__ P3)
{
  int idx = blockIdx.x * 256 + threadIdx.x;     // 14,450,688 = 56,448*256 exact
  int row = idx / 576, k = idx - row * 576;
  int imgL = row / 49, pos = row - imgL * 49;
  int oy = pos / 7, ox = pos - oy * 7;
  int ci = k / 9, r = k - ci * 9;
  int ky = r / 3, kx = r - ky * 3;
  P3[idx] = C2[((size_t)imgL * 81 + (oy + ky) * 9 + ox + kx) * 64 + ci];
}

// ---------------------------------------------------------------- MFMA GEMM, 128x128 tile (kept for reference)
template<int ACT, int OUTMODE>
__global__ __launch_bounds__(256) void gemm_bt(
    const bf16* __restrict__ A, const bf16* __restrict__ W,
    const float* __restrict__ bias, void* __restrict__ outp,
    int M, int N, int K)
{
  __shared__ bf16 As[128*64];
  __shared__ bf16 Bs[128*64];
  const int tid = threadIdx.x;
  const int lane = tid & 63, wave = tid >> 6;
  const int m0 = blockIdx.x * 128, n0 = blockIdx.y * 128;
  const int wm = (wave >> 1) * 64, wn = (wave & 1) * 64;
  const int l16 = lane & 15, l4 = lane >> 4;
  f32x4 acc[4][4];
  #pragma unroll
  for (int i = 0; i < 4; ++i)
    #pragma unroll
    for (int j = 0; j < 4; ++j) { f32x4 z = {0.f,0.f,0.f,0.f}; acc[i][j] = z; }

  for (int k0 = 0; k0 < K; k0 += 64) {
    __syncthreads();
    #pragma unroll
    for (int it = 0; it < 4; ++it) {
      int f = it*256 + tid;
      int row = f >> 3;
      int col = (f & 7) << 3;
      const bf16* ga = A + (size_t)(m0 + row) * K + k0 + col;
      const bf16* gb = W + (size_t)(n0 + row) * K + k0 + col;
      __builtin_amdgcn_global_load_lds((const __attribute__((address_space(1))) void*)ga,
                                       (__attribute__((address_space(3))) void*)(As + f*8), 16, 0, 0);
      __builtin_amdgcn_global_load_lds((const __attribute__((address_space(1))) void*)gb,
                                       (__attribute__((address_space(3))) void*)(Bs + f*8), 16, 0, 0);
    }
    __syncthreads();
    #pragma unroll
    for (int kk = 0; kk < 2; ++kk) {
      short8 af[4], bfr[4];
      #pragma unroll
      for (int i = 0; i < 4; ++i) af[i]  = *(const short8*)(As + (wm + i*16 + l16)*64 + kk*32 + l4*8);
      #pragma unroll
      for (int j = 0; j < 4; ++j) bfr[j] = *(const short8*)(Bs + (wn + j*16 + l16)*64 + kk*32 + l4*8);
      #pragma unroll
      for (int i = 0; i < 4; ++i)
        #pragma unroll
        for (int j = 0; j < 4; ++j)
          acc[i][j] = __builtin_amdgcn_mfma_f32_16x16x32_bf16(af[i], bfr[j], acc[i][j], 0, 0, 0);
    }
  }
  #pragma unroll
  for (int i = 0; i < 4; ++i)
    #pragma unroll
    for (int j = 0; j < 4; ++j)
      #pragma unroll
      for (int r = 0; r < 4; ++r) {
        int grow = m0 + wm + i*16 + l4*4 + r;
        int gcol = n0 + wn + j*16 + l16;
        if (grow < M && gcol < N) {
          float v = acc[i][j][r] + bias[gcol];
          if (ACT == 1) v = tanhf(v);
          else if (ACT == 2) v = 0.5f * v * (1.0f + erff(v * 0.70710678118654752f));
          else if (ACT == 3) v = fmaxf(v, 0.0f);
          size_t idx = (size_t)grow * N + gcol;
          if (OUTMODE == 0)      ((bf16*)outp)[idx] = f2bf(v);
          else if (OUTMODE == 1) ((float*)outp)[idx] = v;
          else                   ((float*)outp)[idx] += v;
        }
      }
}

// ---------------------------------------------------------------- MFMA GEMM, 128x64 tile (more blocks/CU)
template<int ACT, int OUTMODE>
__global__ __launch_bounds__(256) void gemm_bt64(
    const bf16* __restrict__ A, const bf16* __restrict__ W,
    const float* __restrict__ bias, void* __restrict__ outp,
    int M, int N, int K)
{
  __shared__ bf16 As[128*64];
  __shared__ bf16 Bs[64*64];
  const int tid = threadIdx.x;
  const int lane = tid & 63, wave = tid >> 6;
  const int m0 = blockIdx.x * 128, n0 = blockIdx.y * 64;
  const int wm = wave * 32;
  const int l16 = lane & 15, l4 = lane >> 4;
  f32x4 acc[2][4];
  #pragma unroll
  for (int i = 0; i < 2; ++i)
    #pragma unroll
    for (int j = 0; j < 4; ++j) { f32x4 z = {0.f,0.f,0.f,0.f}; acc[i][j] = z; }

  for (int k0 = 0; k0 < K; k0 += 64) {
    __syncthreads();
    #pragma unroll
    for (int it = 0; it < 4; ++it) {          // A: 128x64 = 1024 slots of 8
      int f = it*256 + tid;
      int row = f >> 3, col = (f & 7) << 3;
      const bf16* ga = A + (size_t)(m0 + row) * K + k0 + col;
      __builtin_amdgcn_global_load_lds((const __attribute__((address_space(1))) void*)ga,
                                       (__attribute__((address_space(3))) void*)(As + f*8), 16, 0, 0);
    }
    #pragma unroll
    for (int it = 0; it < 2; ++it) {          // B: 64x64 = 512 slots of 8
      int f = it*256 + tid;
      int row = f >> 3, col = (f & 7) << 3;
      const bf16* gb = W + (size_t)(n0 + row) * K + k0 + col;
      __builtin_amdgcn_global_load_lds((const __attribute__((address_space(1))) void*)gb,
                                       (__attribute__((address_space(3))) void*)(Bs + f*8), 16, 0, 0);
    }
    __syncthreads();
    #pragma unroll
    for (int kk = 0; kk < 2; ++kk) {
      short8 af[2], bfr[4];
      #pragma unroll
      for (int i = 0; i < 2; ++i) af[i]  = *(const short8*)(As + (wm + i*16 + l16)*64 + kk*32 + l4*8);
      #pragma unroll
      for (int j = 0; j < 4; ++j) bfr[j] = *(const short8*)(Bs + (j*16 + l16)*64 + kk*32 + l4*8);
      #pragma unroll
      for (int i = 0; i < 2; ++i)
        #pragma unroll
        for (int j = 0; j < 4; ++j)
          acc[i][j] = __builtin_amdgcn_mfma_f32_16x16x32_bf16(af[i], bfr[j], acc[i][j], 0, 0, 0);
    }
  }
  #pragma unroll
  for (int i = 0; i < 2; ++i)
    #pragma unroll
    for (int j = 0; j < 4; ++j)
      #pragma unroll
      for (int r = 0; r < 4; ++r) {
        int grow = m0 + wm + i*16 + l4*4 + r;
        int gcol = n0 + j*16 + l16;
        if (grow < M && gcol < N) {
          float v = acc[i][j][r] + bias[gcol];
          if (ACT == 1) v = tanhf(v);
          else if (ACT == 2) v = 0.5f * v * (1.0f + erff(v * 0.70710678118654752f));
          else if (ACT == 3) v = fmaxf(v, 0.0f);
          size_t idx = (size_t)grow * N + gcol;
          if (OUTMODE == 0)      ((bf16*)outp)[idx] = f2bf(v);
          else if (OUTMODE == 1) ((float*)outp)[idx] = v;
          else                   ((float*)outp)[idx] += v;
        }
      }
}

// ---------------------------------------------------------------- LayerNorm -> bf16
__global__ __launch_bounds__(256) void ln_kernel(const float* __restrict__ x,
    const float* __restrict__ g, const float* __restrict__ b,
    bf16* __restrict__ out, int rows)
{
  int wave = threadIdx.x >> 6, lane = threadIdx.x & 63;
  int row = blockIdx.x * 4 + wave;
  if (row >= rows) return;
  const float* xr = x + (size_t)row * 768;
  float v[12]; float s = 0.f, s2 = 0.f;
  #pragma unroll
  for (int j = 0; j < 12; ++j) { float t = xr[j*64 + lane]; v[j] = t; s += t; s2 = fmaf(t, t, s2); }
  #pragma unroll
  for (int off = 32; off; off >>= 1) { s += __shfl_xor(s, off); s2 += __shfl_xor(s2, off); }
  float mean = s * (1.0f/768.0f);
  float var  = s2 * (1.0f/768.0f) - mean*mean;
  float rs   = rsqrtf(var + 1e-5f);
  bf16* orow = out + (size_t)row * 768;
  #pragma unroll
  for (int j = 0; j < 12; ++j) { int c = j*64 + lane; orow[c] = f2bf((v[j]-mean)*rs*g[c] + b[c]); }
}

// ---------------------------------------------------------------- token assembly
__global__ __launch_bounds__(256) void assemble_kernel(
    const float* __restrict__ tok_emb, const float* __restrict__ pos_emb,
    const float* __restrict__ gpe, const int* __restrict__ text,
    const int* __restrict__ actions, const int* __restrict__ timesteps,
    const float* __restrict__ act_emb, const float* __restrict__ se,
    float* __restrict__ x)
{
  int idx = blockIdx.x * 256 + threadIdx.x;   // < 32*383*768 = 9,412,608
  if (idx >= 12256 * 768) return;
  int c  = idx % 768;
  int bt = idx / 768;
  int t  = bt % 383;
  int b  = bt / 383;
  float pos = gpe[(size_t)timesteps[b]*768 + c] + pos_emb[t*768 + c];
  float e;
  if (t < 128) {
    e = tok_emb[(size_t)text[b*128 + t]*768 + c];
  } else {
    int r = t - 128;
    if ((r & 1) == 0) e = se[((size_t)b*128 + (r >> 1))*768 + c];
    else              e = tanhf(act_emb[actions[b*128 + ((r+1) >> 1)]*768 + c]);
  }
  x[idx] = e + pos;
}

// ---------------------------------------------------------------- attention: MFMA, trimmed staging (static segments)
__global__ __launch_bounds__(256, 1) void attn_mfma(const bf16* __restrict__ qkv, bf16* __restrict__ yb)
{
  __shared__ __align__(16) unsigned short Ks[384*72];   // K  [t][d], pad 72  (55,296 B)
  __shared__ __align__(16) unsigned short VT[64*392];   // V^T[d][t], pad 392 (50,176 B)
  __shared__ __align__(16) unsigned short Pl[64*392];   // P  [row][t], pad   (50,176 B)
  const int tid = threadIdx.x, wave = tid >> 6, lane = tid & 63;
  const int l16 = lane & 15, l4 = lane >> 4;
  const int b = blockIdx.x / 12, hh = blockIdx.x % 12;
  const int rb = blockIdx.y;                            // 0..5, rows rb*64..rb*64+63
  const size_t qbase = ((size_t)b * 383) * 2304 + (size_t)hh * 64;
  const size_t kbase = qbase + 768;
  const size_t vbase = qbase + 1536;
  const size_t ybase = ((size_t)b * 383) * 768 + (size_t)hh * 64;
  const unsigned short* qk = (const unsigned short*)qkv;

  const int tlim = (rb == 5) ? 383 : (rb*64 + 64);      // keys needed by this row block
  #pragma unroll
  for (int seg = 0; seg < 6; ++seg) {
    if (seg <= rb) {                                    // wave-uniform guard; inner loops compile-time
      #pragma unroll
      for (int it = 0; it < 4; ++it) {
        int f = it*256 + tid;                           // 0..1023 within segment
        if (seg < 5 || f < 1008) {                      // seg 5 has 63 rows (t=383 excluded)
          int t = seg*64 + (f >> 4), d4 = (f & 15) << 2;
          u16x4 kv = *(const u16x4*)(qk + kbase + (size_t)t*2304 + d4);
          u16x4 vv = *(const u16x4*)(qk + vbase + (size_t)t*2304 + d4);
          *(u16x4*)(Ks + t*72 + d4) = kv;
          VT[(d4+0)*392 + t] = vv[0];
          VT[(d4+1)*392 + t] = vv[1];
          VT[(d4+2)*392 + t] = vv[2];
          VT[(d4+3)*392 + t] = vv[3];
        }
      }
    }
  }
  // zero-fill VT tail t in [tlim, 384) so PV's P=0 x VT contributions are exact 0
  if (rb == 5) {
    if (tid < 64) VT[tid*392 + 383] = 0;
  } else {
    const int cnt = (384 - tlim) >> 2;
    const int total = 64 * cnt;
    u16x4 z4 = {0, 0, 0, 0};
    for (int f = tid; f < total; f += 256) {
      int d = f / cnt, j = f - d*cnt;
      *(u16x4*)(VT + d*392 + tlim + j*4) = z4;
    }
  }
  __syncthreads();

  const int qrow0 = rb*64 + wave*16;
  short8 qa[2];
  #pragma unroll
  for (int kk = 0; kk < 2; ++kk)
    qa[kk] = *(const short8*)(qk + qbase + (size_t)(qrow0 + l16)*2304 + kk*32 + l4*8);

  f32x4 sfr[24];
  #pragma unroll
  for (int kt = 0; kt < 24; ++kt) { f32x4 z = {0.f,0.f,0.f,0.f}; sfr[kt] = z; }
  #pragma unroll
  for (int kk = 0; kk < 2; ++kk)
    #pragma unroll
    for (int kt = 0; kt < 24; ++kt) {
      short8 kf = *(const short8*)(Ks + (kt*16 + l16)*72 + kk*32 + l4*8);
      sfr[kt] = __builtin_amdgcn_mfma_f32_16x16x32_bf16(qa[kk], kf, sfr[kt], 0, 0, 0);
    }

  float linv[4];
  #pragma unroll
  for (int r = 0; r < 4; ++r) {
    const int gr = qrow0 + l4*4 + r;
    float mx = -1e30f;
    #pragma unroll
    for (int kt = 0; kt < 24; ++kt) {
      int gk = kt*16 + l16;
      float s = sfr[kt][r] * 0.125f;
      s = (gk <= gr) ? s : -1e30f;
      sfr[kt][r] = s;
      mx = fmaxf(mx, s);
    }
    #pragma unroll
    for (int off = 8; off; off >>= 1) mx = fmaxf(mx, __shfl_xor(mx, off));
    float ls = 0.f;
    #pragma unroll
    for (int kt = 0; kt < 24; ++kt) {
      float p = __expf(sfr[kt][r] - mx);
      ls += p;
      ((bf16*)Pl)[(wave*16 + l4*4 + r)*392 + kt*16 + l16] = f2bf(p);
    }
    #pragma unroll
    for (int off = 8; off; off >>= 1) ls += __shfl_xor(ls, off);
    linv[r] = 1.0f / ls;
  }

  f32x4 acc[4];
  #pragma unroll
  for (int j = 0; j < 4; ++j) { f32x4 z = {0.f,0.f,0.f,0.f}; acc[j] = z; }
  #pragma unroll
  for (int kt2 = 0; kt2 < 12; ++kt2) {
    short8 pf = *(const short8*)(Pl + (wave*16 + l16)*392 + kt2*32 + l4*8);
    #pragma unroll
    for (int j = 0; j < 4; ++j) {
      short8 vf = *(const short8*)(VT + (j*16 + l16)*392 + kt2*32 + l4*8);
      acc[j] = __builtin_amdgcn_mfma_f32_16x16x32_bf16(pf, vf, acc[j], 0, 0, 0);
    }
  }
  #pragma unroll
  for (int j = 0; j < 4; ++j)
    #pragma unroll
    for (int r = 0; r < 4; ++r) {
      int gr = qrow0 + l4*4 + r;
      if (gr < 383)
        yb[ybase + (size_t)gr*768 + j*16 + l16] = f2bf(acc[j][r] * linv[r]);
    }
}

// ---------------------------------------------------------------- head: logits for selected tokens
__global__ __launch_bounds__(256) void head_kernel(const bf16* __restrict__ af,
    const bf16* __restrict__ hw, float* __restrict__ out)
{
  int wave = threadIdx.x >> 6, lane = threadIdx.x & 63;
  int token = blockIdx.x * 4 + wave;       // < 4096
  int b = token >> 7, s = token & 127;
  size_t row = (size_t)b * 383 + 128 + 2*s;
  float av[12];
  #pragma unroll
  for (int j = 0; j < 12; ++j) av[j] = bf2f(af[row*768 + j*64 + lane]);
  for (int vv = 0; vv < 18; ++vv) {
    float p = 0.f;
    #pragma unroll
    for (int j = 0; j < 12; ++j) p = fmaf(av[j], bf2f(hw[vv*768 + j*64 + lane]), p);
    #pragma unroll
    for (int off = 32; off; off >>= 1) p += __shfl_xor(p, off);
    if (lane == 0) out[(size_t)token*18 + vv] = p;
  }
}

// ---------------------------------------------------------------- launch
extern "C" void kernel_launch(void* const* d_in, const int* in_sizes, int n_in,
                              void* d_out, int out_size, void* d_ws, size_t ws_size,
                              hipStream_t stream)
{
  const float* states   = (const float*)d_in[0];
  const int*   actions  = (const int*)d_in[1];
  const int*   text     = (const int*)d_in[2];
  const int*   timestep = (const int*)d_in[3];
  const float* tok_emb  = (const float*)d_in[4];
  const float* pos_emb  = (const float*)d_in[5];
  const float* gpe      = (const float*)d_in[6];
  const float* conv_w1  = (const float*)d_in[7];
  const float* conv_b1  = (const float*)d_in[8];
  const float* conv_w2  = (const float*)d_in[9];
  const float* conv_b2  = (const float*)d_in[10];
  const float* conv_w3  = (const float*)d_in[11];
  const float* conv_b3  = (const float*)d_in[12];
  const float* enc_w    = (const float*)d_in[13];
  const float* enc_b    = (const float*)d_in[14];
  const float* act_emb  = (const float*)d_in[15];
  const float* ln1_g    = (const float*)d_in[16];
  const float* ln1_b    = (const float*)d_in[17];
  const float* ln2_g    = (const float*)d_in[18];
  const float* ln2_b    = (const float*)d_in[19];
  const float* Wq       = (const float*)d_in[20];
  const float* bq       = (const float*)d_in[21];
  const float* Wk       = (const float*)d_in[22];
  const float* bk       = (const float*)d_in[23];
  const float* Wv       = (const float*)d_in[24];
  const float* bv       = (const float*)d_in[25];
  const float* Wo       = (const float*)d_in[26];
  const float* bo       = (const float*)d_in[27];
  const float* m1w      = (const float*)d_in[28];
  const float* m1b      = (const float*)d_in[29];
  const float* m2w      = (const float*)d_in[30];
  const float* m2b      = (const float*)d_in[31];
  const float* lnf_g    = (const float*)d_in[32];
  const float* lnf_b    = (const float*)d_in[33];
  const float* head_w   = (const float*)d_in[34];

  // ---- workspace layout (total 136,937,472 B ~ 137 MB) ----
  char* ws = (char*)d_ws;
  bf16*  wbuf = (bf16*)(ws);                          // 0 .. 4,816,896 (weight staging)
  float* qkvb = (float*)(ws + 4807680);               // 9,216 B bias concat (tail of wbuf region)
  // conv phase (im2col + GEMM, 8 chunks x 512 images):
  char*  A0p  = ws + 4816896;                         // arena base
  bf16*  c3f  = (bf16*)(A0p);                         // [4096*49][64] rows img*49+pos : 25,690,112 B
  char*  S0   = A0p + 25690112;                       // chunk scratch
  bf16*  P1c  = (bf16*)(S0);                          // 26,214,400
  bf16*  C1c  = (bf16*)(S0 + 26214400);               // 13,107,200
  bf16*  P2c  = (bf16*)(S0 + 39321600);               // 42,467,328
  bf16*  C2c  = (bf16*)(S0 + 81788928);               //  5,308,416
  bf16*  P3c  = (bf16*)(S0);                          // 28,901,376 (P1c/C1c dead)
  float* se   = (float*)(A0p + 119537664);            // 12,582,912 (persists to assemble)
  // transformer phase:
  float* x    = (float*)(A0p);                        // 12256*768 f32 = 37,650,432
  bf16*  a    = (bf16*)(ws + 42467328);               // 12288*768 bf16
  char*  R    = ws + 61341696;                        // 75,497,472 shared region
  bf16*  qkv  = (bf16*)(R);                           // 12256*2304 bf16 = 56,512,512
  bf16*  y    = (bf16*)(R + 56623104);                // 12288*768 bf16 = 18,874,368
  bf16*  h    = (bf16*)(R);                           // MLP phase (after qkv consumed)

  // conv weights -> bf16 (w1@0: 2048, w2@2048: 32768, w3@34816: 36864), 4-wide
  cvt_kernel4<<<2,  256, 0, stream>>>(conv_w1, wbuf,          512);
  cvt_kernel4<<<32, 256, 0, stream>>>(conv_w2, wbuf + 2048,  8192);
  cvt_kernel4<<<36, 256, 0, stream>>>(conv_w3, wbuf + 34816, 9216);

  for (int c = 0; c < 8; ++c) {
    const float* st = states + (size_t)c * 512 * 7056;
    im2col1<<<51200, 256, 0, stream>>>(st, P1c);
    gemm_bt64<3,0><<<dim3(1600,1), 256, 0, stream>>>(P1c, wbuf,         conv_b1, C1c, 204800, 32, 64);
    im2col2<<<82944, 256, 0, stream>>>(C1c, P2c);
    gemm_bt64<3,0><<<dim3(324,1),  256, 0, stream>>>(P2c, wbuf + 2048,  conv_b2, C2c, 41472, 64, 512);
    im2col3<<<56448, 256, 0, stream>>>(C2c, P3c);
    gemm_bt64<3,0><<<dim3(196,1),  256, 0, stream>>>(P3c, wbuf + 34816, conv_b3,
                                                     c3f + (size_t)c * 25088 * 64, 25088, 64, 576);
  }

  // se = tanh(c3f @ enc_w'^T + enc_b)
  cvt_enc<<<9408, 256, 0, stream>>>(enc_w, wbuf);
  gemm_bt64<1,1><<<dim3(32, 12), 256, 0, stream>>>(c3f, wbuf, enc_b, se, 4096, 768, 3136);
  assemble_kernel<<<36768, 256, 0, stream>>>(tok_emb, pos_emb, gpe, text, actions, timestep, act_emb, se, x);

  for (int l = 0; l < 12; ++l) {
    ln_kernel<<<3064, 256, 0, stream>>>(x, ln1_g + l*768, ln1_b + l*768, a, 12256);
    cvt_qkv4<<<1731, 256, 0, stream>>>(Wq + (size_t)l*589824, Wk + (size_t)l*589824,
                                       Wv + (size_t)l*589824, bq + l*768, bk + l*768, bv + l*768,
                                       wbuf, qkvb);
    gemm_bt64<0,0><<<dim3(96, 36), 256, 0, stream>>>(a, wbuf, qkvb, qkv, 12256, 2304, 768);
    attn_mfma<<<dim3(384, 6), 256, 0, stream>>>(qkv, y);
    cvt_kernel4<<<576, 256, 0, stream>>>(Wo + (size_t)l*589824, wbuf, 147456);
    gemm_bt64<0,2><<<dim3(96, 12), 256, 0, stream>>>(y, wbuf, bo + l*768, x, 12256, 768, 768);
    ln_kernel<<<3064, 256, 0, stream>>>(x, ln2_g + l*768, ln2_b + l*768, a, 12256);
    cvt_kernel4<<<2304, 256, 0, stream>>>(m1w + (size_t)l*2359296, wbuf, 589824);
    gemm_bt64<2,0><<<dim3(96, 48), 256, 0, stream>>>(a, wbuf, m1b + l*3072, h, 12256, 3072, 768);
    cvt_kernel4<<<2304, 256, 0, stream>>>(m2w + (size_t)l*2359296, wbuf, 589824);
    gemm_bt64<0,2><<<dim3(96, 12), 256, 0, stream>>>(h, wbuf, m2b + l*768, x, 12256, 768, 3072);
  }

  ln_kernel<<<3064, 256, 0, stream>>>(x, lnf_g, lnf_b, a, 12256);
  cvt_kernel4<<<14, 256, 0, stream>>>(head_w, wbuf, 3456);
  head_kernel<<<1024, 256, 0, stream>>>(a, wbuf, (float*)d_out);
}

// Round 25
// 6543.991 us; speedup vs baseline: 1.4705x; 1.0068x over previous
//
#include <hip/hip_runtime.h>
#include <hip/hip_bf16.h>
#include <math.h>

using bf16 = __hip_bfloat16;
typedef __attribute__((ext_vector_type(8))) short short8;
typedef __attribute__((ext_vector_type(4))) short s16x4;
typedef __attribute__((ext_vector_type(4))) float f32x4;
typedef __attribute__((ext_vector_type(4))) unsigned short u16x4;

#define DEVFN __device__ __forceinline__

DEVFN float bf2f(bf16 v) { return __bfloat162float(v); }
DEVFN bf16  f2bf(float v) { return __float2bfloat16(v); }
DEVFN short bfbits(float v) { bf16 h = __float2bfloat16(v); return *reinterpret_cast<short*>(&h); }

// LN body shared by fused kernels (verbatim from ln_kernel -> bit-identical)
DEVFN void ln_body(const float* __restrict__ x, const float* __restrict__ g,
                   const float* __restrict__ b, bf16* __restrict__ out, int rows, int blk)
{
  int wave = threadIdx.x >> 6, lane = threadIdx.x & 63;
  int row = blk * 4 + wave;
  if (row >= rows) return;
  const float* xr = x + (size_t)row * 768;
  float v[12]; float s = 0.f, s2 = 0.f;
  #pragma unroll
  for (int j = 0; j < 12; ++j) { float t = xr[j*64 + lane]; v[j] = t; s += t; s2 = fmaf(t, t, s2); }
  #pragma unroll
  for (int off = 32; off; off >>= 1) { s += __shfl_xor(s, off); s2 += __shfl_xor(s2, off); }
  float mean = s * (1.0f/768.0f);
  float var  = s2 * (1.0f/768.0f) - mean*mean;
  float rs   = rsqrtf(var + 1e-5f);
  bf16* orow = out + (size_t)row * 768;
  #pragma unroll
  for (int j = 0; j < 12; ++j) { int c = j*64 + lane; orow[c] = f2bf((v[j]-mean)*rs*g[c] + b[c]); }
}

// ---------------------------------------------------------------- f32 -> bf16, 4-wide
__global__ __launch_bounds__(256) void cvt_kernel4(const float* __restrict__ in, bf16* __restrict__ out, int n4)
{
  int i = blockIdx.x * 256 + threadIdx.x;
  if (i < n4) {
    float4 v = ((const float4*)in)[i];
    s16x4 o = { bfbits(v.x), bfbits(v.y), bfbits(v.z), bfbits(v.w) };
    *(s16x4*)(out + (size_t)i * 4) = o;
  }
}

// ---------------------------------------------------------------- LN (blocks<3064) + generic cvt4 (rest)
__global__ __launch_bounds__(256) void ln_cvt4(const float* __restrict__ x,
    const float* __restrict__ g, const float* __restrict__ b, bf16* __restrict__ out, int rows,
    const float* __restrict__ cin, bf16* __restrict__ cout, int n4)
{
  int bid = blockIdx.x;
  if (bid < 3064) { ln_body(x, g, b, out, rows, bid); return; }
  int i = (bid - 3064) * 256 + threadIdx.x;
  if (i < n4) {
    float4 v = ((const float4*)cin)[i];
    s16x4 o = { bfbits(v.x), bfbits(v.y), bfbits(v.z), bfbits(v.w) };
    *(s16x4*)(cout + (size_t)i * 4) = o;
  }
}

// ---------------------------------------------------------------- LN (blocks<3064) + QKV weight/bias cvt
__global__ __launch_bounds__(256) void ln_cvtqkv(const float* __restrict__ x,
    const float* __restrict__ g, const float* __restrict__ b, bf16* __restrict__ out, int rows,
    const float* __restrict__ wq, const float* __restrict__ wk, const float* __restrict__ wv,
    const float* __restrict__ bq, const float* __restrict__ bk, const float* __restrict__ bv,
    bf16* __restrict__ wout, float* __restrict__ bout)
{
  int bid = blockIdx.x;
  if (bid < 3064) { ln_body(x, g, b, out, rows, bid); return; }
  int i = (bid - 3064) * 256 + threadIdx.x;     // 1731 cvt blocks
  if (i < 442368) {
    int e = i * 4;
    const float* src = (e < 589824) ? (wq + e)
                     : (e < 1179648) ? (wk + (e - 589824))
                     : (wv + (e - 1179648));
    float4 v = *(const float4*)src;
    s16x4 o = { bfbits(v.x), bfbits(v.y), bfbits(v.z), bfbits(v.w) };
    *(s16x4*)(wout + (size_t)e) = o;
  } else if (i < 442944) {
    int j = (i - 442368) * 4;
    #pragma unroll
    for (int t = 0; t < 4; ++t) {
      int c = j + t;
      bout[c] = (c < 768) ? bq[c] : (c < 1536) ? bk[c - 768] : bv[c - 1536];
    }
  }
}

// enc_w column permutation: out[n][pos*64+co] = in[n][co*49+pos]  (768 x 3136)
__global__ __launch_bounds__(256) void cvt_enc(const float* __restrict__ in, bf16* __restrict__ out)
{
  int i = blockIdx.x * 256 + threadIdx.x;       // 2,408,448 = 9408*256 exact
  int n = i / 3136, kp = i - n * 3136;
  int pos = kp >> 6, co = kp & 63;
  out[i] = f2bf(in[n * 3136 + co * 49 + pos]);
}

// ---------------------------------------------------------------- im2col kernels (per 512-image chunk)
__global__ __launch_bounds__(256) void im2col1(const float* __restrict__ states, bf16* __restrict__ P1)
{
  int idx = blockIdx.x * 256 + threadIdx.x;     // 13,107,200 = 51,200*256 exact
  int row = idx >> 6, k = idx & 63;
  int imgL = row / 400, pos = row - imgL * 400;
  int oy = pos / 20, ox = pos - oy * 20;
  int ky = k >> 3, kx = k & 7;
  float v = states[(size_t)imgL * 7056 + (oy * 4 + ky) * 84 + ox * 4 + kx] * (1.0f / 255.0f);
  P1[idx] = f2bf(v);
}

__global__ __launch_bounds__(256) void im2col2(const bf16* __restrict__ C1, bf16* __restrict__ P2)
{
  int idx = blockIdx.x * 256 + threadIdx.x;     // 21,233,664 = 82,944*256 exact
  int row = idx >> 9, k = idx & 511;
  int imgL = row / 81, pos = row - imgL * 81;
  int oy = pos / 9, ox = pos - oy * 9;
  int ci = k >> 4, r = k & 15, ky = r >> 2, kx = r & 3;
  P2[idx] = C1[((size_t)imgL * 400 + (oy * 2 + ky) * 20 + ox * 2 + kx) * 32 + ci];
}

__global__ __launch_bounds__(256) void im2col3(const bf16* __restrict__ C2, bf16* __restrict__ P3)
{
  int idx = blockIdx.x * 256 + threadIdx.x;     // 14,450,688 = 56,448*256 exact
  int row = idx / 576, k = idx - row * 576;
  int imgL = row / 49, pos = row - imgL * 49;
  int oy = pos / 7, ox = pos - oy * 7;
  int ci = k / 9, r = k - ci * 9;
  int ky = r / 3, kx = r - ky * 3;
  P3[idx] = C2[((size_t)imgL * 81 + (oy + ky) * 9 + ox + kx) * 64 + ci];
}

// ---------------------------------------------------------------- MFMA GEMM, 128x64 tile (more blocks/CU)
template<int ACT, int OUTMODE>
__global__ __launch_bounds__(256) void gemm_bt64(
    const bf16* __restrict__ A, const bf16* __restrict__ W,
    const float* __restrict__ bias, void* __restrict__ outp,
    int M, int N, int K)
{
  __shared__ bf16 As[128*64];
  __shared__ bf16 Bs[64*64];
  const int tid = threadIdx.x;
  const int lane = tid & 63, wave = tid >> 6;
  const int m0 = blockIdx.x * 128, n0 = blockIdx.y * 64;
  const int wm = wave * 32;
  const int l16 = lane & 15, l4 = lane >> 4;
  f32x4 acc[2][4];
  #pragma unroll
  for (int i = 0; i < 2; ++i)
    #pragma unroll
    for (int j = 0; j < 4; ++j) { f32x4 z = {0.f,0.f,0.f,0.f}; acc[i][j] = z; }

  for (int k0 = 0; k0 < K; k0 += 64) {
    __syncthreads();
    #pragma unroll
    for (int it = 0; it < 4; ++it) {          // A: 128x64 = 1024 slots of 8
      int f = it*256 + tid;
      int row = f >> 3, col = (f & 7) << 3;
      const bf16* ga = A + (size_t)(m0 + row) * K + k0 + col;
      __builtin_amdgcn_global_load_lds((const __attribute__((address_space(1))) void*)ga,
                                       (__attribute__((address_space(3))) void*)(As + f*8), 16, 0, 0);
    }
    #pragma unroll
    for (int it = 0; it < 2; ++it) {          // B: 64x64 = 512 slots of 8
      int f = it*256 + tid;
      int row = f >> 3, col = (f & 7) << 3;
      const bf16* gb = W + (size_t)(n0 + row) * K + k0 + col;
      __builtin_amdgcn_global_load_lds((const __attribute__((address_space(1))) void*)gb,
                                       (__attribute__((address_space(3))) void*)(Bs + f*8), 16, 0, 0);
    }
    __syncthreads();
    #pragma unroll
    for (int kk = 0; kk < 2; ++kk) {
      short8 af[2], bfr[4];
      #pragma unroll
      for (int i = 0; i < 2; ++i) af[i]  = *(const short8*)(As + (wm + i*16 + l16)*64 + kk*32 + l4*8);
      #pragma unroll
      for (int j = 0; j < 4; ++j) bfr[j] = *(const short8*)(Bs + (j*16 + l16)*64 + kk*32 + l4*8);
      #pragma unroll
      for (int i = 0; i < 2; ++i)
        #pragma unroll
        for (int j = 0; j < 4; ++j)
          acc[i][j] = __builtin_amdgcn_mfma_f32_16x16x32_bf16(af[i], bfr[j], acc[i][j], 0, 0, 0);
    }
  }
  #pragma unroll
  for (int i = 0; i < 2; ++i)
    #pragma unroll
    for (int j = 0; j < 4; ++j)
      #pragma unroll
      for (int r = 0; r < 4; ++r) {
        int grow = m0 + wm + i*16 + l4*4 + r;
        int gcol = n0 + j*16 + l16;
        if (grow < M && gcol < N) {
          float v = acc[i][j][r] + bias[gcol];
          if (ACT == 1) v = tanhf(v);
          else if (ACT == 2) v = 0.5f * v * (1.0f + erff(v * 0.70710678118654752f));
          else if (ACT == 3) v = fmaxf(v, 0.0f);
          size_t idx = (size_t)grow * N + gcol;
          if (OUTMODE == 0)      ((bf16*)outp)[idx] = f2bf(v);
          else if (OUTMODE == 1) ((float*)outp)[idx] = v;
          else                   ((float*)outp)[idx] += v;
        }
      }
}

// ---------------------------------------------------------------- token assembly
__global__ __launch_bounds__(256) void assemble_kernel(
    const float* __restrict__ tok_emb, const float* __restrict__ pos_emb,
    const float* __restrict__ gpe, const int* __restrict__ text,
    const int* __restrict__ actions, const int* __restrict__ timesteps,
    const float* __restrict__ act_emb, const float* __restrict__ se,
    float* __restrict__ x)
{
  int idx = blockIdx.x * 256 + threadIdx.x;   // < 32*383*768 = 9,412,608
  if (idx >= 12256 * 768) return;
  int c  = idx % 768;
  int bt = idx / 768;
  int t  = bt % 383;
  int b  = bt / 383;
  float pos = gpe[(size_t)timesteps[b]*768 + c] + pos_emb[t*768 + c];
  float e;
  if (t < 128) {
    e = tok_emb[(size_t)text[b*128 + t]*768 + c];
  } else {
    int r = t - 128;
    if ((r & 1) == 0) e = se[((size_t)b*128 + (r >> 1))*768 + c];
    else              e = tanhf(act_emb[actions[b*128 + ((r+1) >> 1)]*768 + c]);
  }
  x[idx] = e + pos;
}

// ---------------------------------------------------------------- attention: MFMA, trimmed staging (static segments)
__global__ __launch_bounds__(256, 1) void attn_mfma(const bf16* __restrict__ qkv, bf16* __restrict__ yb)
{
  __shared__ __align__(16) unsigned short Ks[384*72];   // K  [t][d], pad 72  (55,296 B)
  __shared__ __align__(16) unsigned short VT[64*392];   // V^T[d][t], pad 392 (50,176 B)
  __shared__ __align__(16) unsigned short Pl[64*392];   // P  [row][t], pad   (50,176 B)
  const int tid = threadIdx.x, wave = tid >> 6, lane = tid & 63;
  const int l16 = lane & 15, l4 = lane >> 4;
  const int b = blockIdx.x / 12, hh = blockIdx.x % 12;
  const int rb = blockIdx.y;                            // 0..5, rows rb*64..rb*64+63
  const size_t qbase = ((size_t)b * 383) * 2304 + (size_t)hh * 64;
  const size_t kbase = qbase + 768;
  const size_t vbase = qbase + 1536;
  const size_t ybase = ((size_t)b * 383) * 768 + (size_t)hh * 64;
  const unsigned short* qk = (const unsigned short*)qkv;

  const int tlim = (rb == 5) ? 383 : (rb*64 + 64);      // keys needed by this row block
  #pragma unroll
  for (int seg = 0; seg < 6; ++seg) {
    if (seg <= rb) {                                    // wave-uniform guard; inner loops compile-time
      #pragma unroll
      for (int it = 0; it < 4; ++it) {
        int f = it*256 + tid;                           // 0..1023 within segment
        if (seg < 5 || f < 1008) {                      // seg 5 has 63 rows (t=383 excluded)
          int t = seg*64 + (f >> 4), d4 = (f & 15) << 2;
          u16x4 kv = *(const u16x4*)(qk + kbase + (size_t)t*2304 + d4);
          u16x4 vv = *(const u16x4*)(qk + vbase + (size_t)t*2304 + d4);
          *(u16x4*)(Ks + t*72 + d4) = kv;
          VT[(d4+0)*392 + t] = vv[0];
          VT[(d4+1)*392 + t] = vv[1];
          VT[(d4+2)*392 + t] = vv[2];
          VT[(d4+3)*392 + t] = vv[3];
        }
      }
    }
  }
  // zero-fill VT tail t in [tlim, 384) so PV's P=0 x VT contributions are exact 0
  if (rb == 5) {
    if (tid < 64) VT[tid*392 + 383] = 0;
  } else {
    const int cnt = (384 - tlim) >> 2;
    const int total = 64 * cnt;
    u16x4 z4 = {0, 0, 0, 0};
    for (int f = tid; f < total; f += 256) {
      int d = f / cnt, j = f - d*cnt;
      *(u16x4*)(VT + d*392 + tlim + j*4) = z4;
    }
  }
  __syncthreads();

  const int qrow0 = rb*64 + wave*16;
  short8 qa[2];
  #pragma unroll
  for (int kk = 0; kk < 2; ++kk)
    qa[kk] = *(const short8*)(qk + qbase + (size_t)(qrow0 + l16)*2304 + kk*32 + l4*8);

  f32x4 sfr[24];
  #pragma unroll
  for (int kt = 0; kt < 24; ++kt) { f32x4 z = {0.f,0.f,0.f,0.f}; sfr[kt] = z; }
  #pragma unroll
  for (int kk = 0; kk < 2; ++kk)
    #pragma unroll
    for (int kt = 0; kt < 24; ++kt) {
      short8 kf = *(const short8*)(Ks + (kt*16 + l16)*72 + kk*32 + l4*8);
      sfr[kt] = __builtin_amdgcn_mfma_f32_16x16x32_bf16(qa[kk], kf, sfr[kt], 0, 0, 0);
    }

  float linv[4];
  #pragma unroll
  for (int r = 0; r < 4; ++r) {
    const int gr = qrow0 + l4*4 + r;
    float mx = -1e30f;
    #pragma unroll
    for (int kt = 0; kt < 24; ++kt) {
      int gk = kt*16 + l16;
      float s = sfr[kt][r] * 0.125f;
      s = (gk <= gr) ? s : -1e30f;
      sfr[kt][r] = s;
      mx = fmaxf(mx, s);
    }
    #pragma unroll
    for (int off = 8; off; off >>= 1) mx = fmaxf(mx, __shfl_xor(mx, off));
    float ls = 0.f;
    #pragma unroll
    for (int kt = 0; kt < 24; ++kt) {
      float p = __expf(sfr[kt][r] - mx);
      ls += p;
      ((bf16*)Pl)[(wave*16 + l4*4 + r)*392 + kt*16 + l16] = f2bf(p);
    }
    #pragma unroll
    for (int off = 8; off; off >>= 1) ls += __shfl_xor(ls, off);
    linv[r] = 1.0f / ls;
  }

  f32x4 acc[4];
  #pragma unroll
  for (int j = 0; j < 4; ++j) { f32x4 z = {0.f,0.f,0.f,0.f}; acc[j] = z; }
  #pragma unroll
  for (int kt2 = 0; kt2 < 12; ++kt2) {
    short8 pf = *(const short8*)(Pl + (wave*16 + l16)*392 + kt2*32 + l4*8);
    #pragma unroll
    for (int j = 0; j < 4; ++j) {
      short8 vf = *(const short8*)(VT + (j*16 + l16)*392 + kt2*32 + l4*8);
      acc[j] = __builtin_amdgcn_mfma_f32_16x16x32_bf16(pf, vf, acc[j], 0, 0, 0);
    }
  }
  #pragma unroll
  for (int j = 0; j < 4; ++j)
    #pragma unroll
    for (int r = 0; r < 4; ++r) {
      int gr = qrow0 + l4*4 + r;
      if (gr < 383)
        yb[ybase + (size_t)gr*768 + j*16 + l16] = f2bf(acc[j][r] * linv[r]);
    }
}

// ---------------------------------------------------------------- head: logits for selected tokens
__global__ __launch_bounds__(256) void head_kernel(const bf16* __restrict__ af,
    const bf16* __restrict__ hw, float* __restrict__ out)
{
  int wave = threadIdx.x >> 6, lane = threadIdx.x & 63;
  int token = blockIdx.x * 4 + wave;       // < 4096
  int b = token >> 7, s = token & 127;
  size_t row = (size_t)b * 383 + 128 + 2*s;
  float av[12];
  #pragma unroll
  for (int j = 0; j < 12; ++j) av[j] = bf2f(af[row*768 + j*64 + lane]);
  for (int vv = 0; vv < 18; ++vv) {
    float p = 0.f;
    #pragma unroll
    for (int j = 0; j < 12; ++j) p = fmaf(av[j], bf2f(hw[vv*768 + j*64 + lane]), p);
    #pragma unroll
    for (int off = 32; off; off >>= 1) p += __shfl_xor(p, off);
    if (lane == 0) out[(size_t)token*18 + vv] = p;
  }
}

// ---------------------------------------------------------------- launch
extern "C" void kernel_launch(void* const* d_in, const int* in_sizes, int n_in,
                              void* d_out, int out_size, void* d_ws, size_t ws_size,
                              hipStream_t stream)
{
  const float* states   = (const float*)d_in[0];
  const int*   actions  = (const int*)d_in[1];
  const int*   text     = (const int*)d_in[2];
  const int*   timestep = (const int*)d_in[3];
  const float* tok_emb  = (const float*)d_in[4];
  const float* pos_emb  = (const float*)d_in[5];
  const float* gpe      = (const float*)d_in[6];
  const float* conv_w1  = (const float*)d_in[7];
  const float* conv_b1  = (const float*)d_in[8];
  const float* conv_w2  = (const float*)d_in[9];
  const float* conv_b2  = (const float*)d_in[10];
  const float* conv_w3  = (const float*)d_in[11];
  const float* conv_b3  = (const float*)d_in[12];
  const float* enc_w    = (const float*)d_in[13];
  const float* enc_b    = (const float*)d_in[14];
  const float* act_emb  = (const float*)d_in[15];
  const float* ln1_g    = (const float*)d_in[16];
  const float* ln1_b    = (const float*)d_in[17];
  const float* ln2_g    = (const float*)d_in[18];
  const float* ln2_b    = (const float*)d_in[19];
  const float* Wq       = (const float*)d_in[20];
  const float* bq       = (const float*)d_in[21];
  const float* Wk       = (const float*)d_in[22];
  const float* bk       = (const float*)d_in[23];
  const float* Wv       = (const float*)d_in[24];
  const float* bv       = (const float*)d_in[25];
  const float* Wo       = (const float*)d_in[26];
  const float* bo       = (const float*)d_in[27];
  const float* m1w      = (const float*)d_in[28];
  const float* m1b      = (const float*)d_in[29];
  const float* m2w      = (const float*)d_in[30];
  const float* m2b      = (const float*)d_in[31];
  const float* lnf_g    = (const float*)d_in[32];
  const float* lnf_b    = (const float*)d_in[33];
  const float* head_w   = (const float*)d_in[34];

  // ---- workspace layout (total 136,937,472 B ~ 137 MB) ----
  char* ws = (char*)d_ws;
  bf16*  wbuf = (bf16*)(ws);                          // 0 .. 4,816,896 (weight staging)
  float* qkvb = (float*)(ws + 4807680);               // 9,216 B bias concat (tail of wbuf region)
  // conv phase (im2col + GEMM, 8 chunks x 512 images):
  char*  A0p  = ws + 4816896;                         // arena base
  bf16*  c3f  = (bf16*)(A0p);                         // [4096*49][64] rows img*49+pos : 25,690,112 B
  char*  S0   = A0p + 25690112;                       // chunk scratch
  bf16*  P1c  = (bf16*)(S0);                          // 26,214,400
  bf16*  C1c  = (bf16*)(S0 + 26214400);               // 13,107,200
  bf16*  P2c  = (bf16*)(S0 + 39321600);               // 42,467,328
  bf16*  C2c  = (bf16*)(S0 + 81788928);               //  5,308,416
  bf16*  P3c  = (bf16*)(S0);                          // 28,901,376 (P1c/C1c dead)
  float* se   = (float*)(A0p + 119537664);            // 12,582,912 (persists to assemble)
  // transformer phase:
  float* x    = (float*)(A0p);                        // 12256*768 f32 = 37,650,432
  bf16*  a    = (bf16*)(ws + 42467328);               // 12288*768 bf16
  char*  R    = ws + 61341696;                        // 75,497,472 shared region
  bf16*  qkv  = (bf16*)(R);                           // 12256*2304 bf16 = 56,512,512
  bf16*  y    = (bf16*)(R + 56623104);                // 12288*768 bf16 = 18,874,368
  bf16*  h    = (bf16*)(R);                           // MLP phase (after qkv consumed)

  // conv weights -> bf16 (w1@0: 2048, w2@2048: 32768, w3@34816: 36864), 4-wide
  cvt_kernel4<<<2,  256, 0, stream>>>(conv_w1, wbuf,          512);
  cvt_kernel4<<<32, 256, 0, stream>>>(conv_w2, wbuf + 2048,  8192);
  cvt_kernel4<<<36, 256, 0, stream>>>(conv_w3, wbuf + 34816, 9216);

  for (int c = 0; c < 8; ++c) {
    const float* st = states + (size_t)c * 512 * 7056;
    im2col1<<<51200, 256, 0, stream>>>(st, P1c);
    gemm_bt64<3,0><<<dim3(1600,1), 256, 0, stream>>>(P1c, wbuf,         conv_b1, C1c, 204800, 32, 64);
    im2col2<<<82944, 256, 0, stream>>>(C1c, P2c);
    gemm_bt64<3,0><<<dim3(324,1),  256, 0, stream>>>(P2c, wbuf + 2048,  conv_b2, C2c, 41472, 64, 512);
    im2col3<<<56448, 256, 0, stream>>>(C2c, P3c);
    gemm_bt64<3,0><<<dim3(196,1),  256, 0, stream>>>(P3c, wbuf + 34816, conv_b3,
                                                     c3f + (size_t)c * 25088 * 64, 25088, 64, 576);
  }

  // se = tanh(c3f @ enc_w'^T + enc_b)
  cvt_enc<<<9408, 256, 0, stream>>>(enc_w, wbuf);
  gemm_bt64<1,1><<<dim3(32, 12), 256, 0, stream>>>(c3f, wbuf, enc_b, se, 4096, 768, 3136);
  assemble_kernel<<<36768, 256, 0, stream>>>(tok_emb, pos_emb, gpe, text, actions, timestep, act_emb, se, x);

  for (int l = 0; l < 12; ++l) {
    // fused: LN1 (x->a) + QKV weight/bias conversion (independent work)
    ln_cvtqkv<<<4795, 256, 0, stream>>>(x, ln1_g + l*768, ln1_b + l*768, a, 12256,
                                        Wq + (size_t)l*589824, Wk + (size_t)l*589824,
                                        Wv + (size_t)l*589824, bq + l*768, bk + l*768, bv + l*768,
                                        wbuf, qkvb);
    gemm_bt64<0,0><<<dim3(96, 36), 256, 0, stream>>>(a, wbuf, qkvb, qkv, 12256, 2304, 768);
    attn_mfma<<<dim3(384, 6), 256, 0, stream>>>(qkv, y);
    cvt_kernel4<<<576, 256, 0, stream>>>(Wo + (size_t)l*589824, wbuf, 147456);
    gemm_bt64<0,2><<<dim3(96, 12), 256, 0, stream>>>(y, wbuf, bo + l*768, x, 12256, 768, 768);
    // fused: LN2 (x->a) + m1 weight conversion
    ln_cvt4<<<5368, 256, 0, stream>>>(x, ln2_g + l*768, ln2_b + l*768, a, 12256,
                                      m1w + (size_t)l*2359296, wbuf, 589824);
    gemm_bt64<2,0><<<dim3(96, 48), 256, 0, stream>>>(a, wbuf, m1b + l*3072, h, 12256, 3072, 768);
    cvt_kernel4<<<2304, 256, 0, stream>>>(m2w + (size_t)l*2359296, wbuf, 589824);
    gemm_bt64<0,2><<<dim3(96, 12), 256, 0, stream>>>(h, wbuf, m2b + l*768, x, 12256, 768, 3072);
  }

  // fused: final LN + head weight conversion
  ln_cvt4<<<3078, 256, 0, stream>>>(x, lnf_g, lnf_b, a, 12256, head_w, wbuf, 3456);
  head_kernel<<<1024, 256, 0, stream>>>(a, wbuf, (float*)d_out);
}